// Round 2
// baseline (17970.613 us; speedup 1.0000x reference)
//
#include <hip/hip_runtime.h>
#include <hip/hip_bf16.h>
#include <math.h>

using bf16 = __hip_bfloat16;

constexpr int S = 4096, D = 1024, H = 16, HD = 64, FF = 4096;

static __device__ __forceinline__ float tof(bf16 v) { return __bfloat162float(v); }
static __device__ __forceinline__ float tof(float v) { return v; }
static __device__ __forceinline__ bf16 tob(float v) { return __float2bfloat16(v); }

// ---------------- LayerNorm: one block (256 thr) per row of D=1024 ----------
// Input fp32, output bf16 (internal activation dtype).
__global__ void ln_kernel(const float* __restrict__ x, const float* __restrict__ scale,
                          const float* __restrict__ bias, bf16* __restrict__ y) {
    int row = blockIdx.x, t = threadIdx.x;
    const float* xr = x + (size_t)row * D;
    float v[4];
    float s = 0.f, ss = 0.f;
#pragma unroll
    for (int i = 0; i < 4; ++i) {
        v[i] = xr[t + 256 * i];
        s += v[i];
        ss += v[i] * v[i];
    }
    __shared__ float r0[256], r1[256];
    r0[t] = s; r1[t] = ss;
    __syncthreads();
    for (int off = 128; off; off >>= 1) {
        if (t < off) { r0[t] += r0[t + off]; r1[t] += r1[t + off]; }
        __syncthreads();
    }
    float mu  = r0[0] * (1.f / D);
    float var = r1[0] * (1.f / D) - mu * mu;
    float inv = rsqrtf(var + 1e-6f);
    bf16* yr = y + (size_t)row * D;
#pragma unroll
    for (int i = 0; i < 4; ++i) {
        int c = t + 256 * i;
        yr[c] = tob((v[i] - mu) * inv * scale[c] + bias[c]);
    }
}

// ---------------- Generic tiled GEMM: C[M,N] = A[M,K]*B[K,N] + bias ----------
// A: bf16 activations. B: fp32 weights. bias: fp32.
#define EPI_NONE 0  // out bf16 = acc + bias
#define EPI_RES  1  // out f32  = acc + bias + resid(f32)
#define EPI_GELU 2  // out bf16 = gelu_exact(acc + bias)

template <int EPI>
__global__ void gemm_kernel(const bf16* __restrict__ A, const float* __restrict__ B,
                            const float* __restrict__ bias, const float* __restrict__ resid,
                            void* __restrict__ out, int M, int N, int K) {
    __shared__ float As[16][65];  // [kk][row], padded
    __shared__ float Bs[16][64];  // [kk][col]
    int tx = threadIdx.x, ty = threadIdx.y;
    int tid = ty * 16 + tx;
    int rowBase = blockIdx.y * 64, colBase = blockIdx.x * 64;
    float acc[4][4] = {};
    for (int k0 = 0; k0 < K; k0 += 16) {
#pragma unroll
        for (int p = 0; p < 4; ++p) {  // A tile 64 rows x 16 k
            int lin = tid + p * 256;
            int r = lin >> 4, kk = lin & 15;
            As[kk][r] = tof(A[(size_t)(rowBase + r) * K + k0 + kk]);
        }
#pragma unroll
        for (int p = 0; p < 4; ++p) {  // B tile 16 k x 64 cols (coalesced)
            int lin = tid + p * 256;
            int kk = lin >> 6, c = lin & 63;
            Bs[kk][c] = B[(size_t)(k0 + kk) * N + colBase + c];
        }
        __syncthreads();
#pragma unroll
        for (int kk = 0; kk < 16; ++kk) {
            float a[4], b[4];
#pragma unroll
            for (int i = 0; i < 4; ++i) a[i] = As[kk][ty * 4 + i];
#pragma unroll
            for (int j = 0; j < 4; ++j) b[j] = Bs[kk][tx * 4 + j];
#pragma unroll
            for (int i = 0; i < 4; ++i)
#pragma unroll
                for (int j = 0; j < 4; ++j) acc[i][j] = fmaf(a[i], b[j], acc[i][j]);
        }
        __syncthreads();
    }
#pragma unroll
    for (int i = 0; i < 4; ++i) {
        int r = rowBase + ty * 4 + i;
#pragma unroll
        for (int j = 0; j < 4; ++j) {
            int c = colBase + tx * 4 + j;
            float val = acc[i][j] + bias[c];
            size_t idx = (size_t)r * N + c;
            if (EPI == EPI_NONE) {
                ((bf16*)out)[idx] = tob(val);
            } else if (EPI == EPI_RES) {
                ((float*)out)[idx] = val + resid[idx];
            } else {  // EPI_GELU
                float g = 0.5f * val * (1.f + erff(val * 0.70710678118f));
                ((bf16*)out)[idx] = tob(g);
            }
        }
    }
}

// ---------------- RoPE in place on (S,H,HD) bf16 tensor ---------------------
__global__ void rope_kernel(bf16* __restrict__ t) {
    int idx = blockIdx.x * 256 + threadIdx.x;  // S*H*32 pair-slots
    int s = idx >> 9;
    int rem = idx & 511;
    int h = rem >> 5, c = rem & 31;
    // freq = 10000^(-c/32) = exp(-c * ln(10000)/32)
    float freq = expf(-(float)c * (9.210340371976184f / 32.f));
    float ang = (float)s * freq;
    float sn, cs;
    sincosf(ang, &sn, &cs);  // accurate range reduction (ang up to ~4095)
    size_t base = (size_t)s * D + h * 64 + c;
    float x1 = tof(t[base]), x2 = tof(t[base + 32]);
    t[base]      = tob(x1 * cs - x2 * sn);
    t[base + 32] = tob(x2 * cs + x1 * sn);
}

// ---------------- Attention: one wave per (head, q-row), online softmax ------
__global__ void attn_kernel(const bf16* __restrict__ q, const bf16* __restrict__ k,
                            const bf16* __restrict__ v, bf16* __restrict__ o) {
    int wid = threadIdx.x >> 6, lane = threadIdx.x & 63;
    int row = blockIdx.x * 4 + wid;  // row = h*S + qr  (waves in a block share head -> K/V L2 reuse)
    int h = row >> 12, qr = row & 4095;
    float qv = tof(q[(size_t)qr * D + h * 64 + lane]) * 0.125f;  // fold 1/sqrt(64)
    const bf16* kh = k + h * 64;
    const bf16* vh = v + h * 64;
    float m = -INFINITY, l = 0.f, acc = 0.f;
    for (int kr = 0; kr < 4096; ++kr) {
        float s = qv * tof(kh[(size_t)kr * D + lane]);
#pragma unroll
        for (int off = 32; off; off >>= 1) s += __shfl_xor(s, off, 64);
        float mn = fmaxf(m, s);
        float corr = __expf(m - mn);  // first iter: exp(-inf)=0
        float p = __expf(s - mn);
        l = l * corr + p;
        acc = acc * corr + p * tof(vh[(size_t)kr * D + lane]);
        m = mn;
    }
    o[(size_t)qr * D + h * 64 + lane] = tob(acc / l);
}

extern "C" void kernel_launch(void* const* d_in, const int* in_sizes, int n_in,
                              void* d_out, int out_size, void* d_ws, size_t ws_size,
                              hipStream_t stream) {
    const float* x   = (const float*)d_in[0];
    const float* s1  = (const float*)d_in[1];
    const float* b1n = (const float*)d_in[2];
    const float* s2  = (const float*)d_in[3];
    const float* b2n = (const float*)d_in[4];
    const float* Wq  = (const float*)d_in[5];
    const float* bq  = (const float*)d_in[6];
    const float* Wk  = (const float*)d_in[7];
    const float* bk  = (const float*)d_in[8];
    const float* Wv  = (const float*)d_in[9];
    const float* bv  = (const float*)d_in[10];
    const float* Wo  = (const float*)d_in[11];
    const float* bo  = (const float*)d_in[12];
    const float* W1  = (const float*)d_in[13];
    const float* b1  = (const float*)d_in[14];
    const float* W2  = (const float*)d_in[15];
    const float* b2  = (const float*)d_in[16];

    char* ws = (char*)d_ws;
    bf16*  y   = (bf16*)(ws);                        // 8 MiB
    bf16*  q   = (bf16*)(ws + (8ull  << 20));        // 8 MiB
    bf16*  k   = (bf16*)(ws + (16ull << 20));        // 8 MiB
    bf16*  v   = (bf16*)(ws + (24ull << 20));        // 8 MiB
    bf16*  o   = (bf16*)(ws + (32ull << 20));        // 8 MiB
    float* x1  = (float*)(ws + (40ull << 20));       // 16 MiB (fp32 residual)
    bf16*  y2  = (bf16*)(ws + (56ull << 20));        // 8 MiB
    bf16*  hb  = (bf16*)(ws + (64ull << 20));        // 32 MiB -> total 96 MiB

    dim3 blk(16, 16);

    ln_kernel<<<S, 256, 0, stream>>>(x, s1, b1n, y);

    gemm_kernel<EPI_NONE><<<dim3(D / 64, S / 64), blk, 0, stream>>>(y, Wq, bq, nullptr, q, S, D, D);
    gemm_kernel<EPI_NONE><<<dim3(D / 64, S / 64), blk, 0, stream>>>(y, Wk, bk, nullptr, k, S, D, D);
    gemm_kernel<EPI_NONE><<<dim3(D / 64, S / 64), blk, 0, stream>>>(y, Wv, bv, nullptr, v, S, D, D);

    rope_kernel<<<(S * H * 32) / 256, 256, 0, stream>>>(q);
    rope_kernel<<<(S * H * 32) / 256, 256, 0, stream>>>(k);

    attn_kernel<<<(S * H) / 4, 256, 0, stream>>>(q, k, v, o);

    gemm_kernel<EPI_RES><<<dim3(D / 64, S / 64), blk, 0, stream>>>(o, Wo, bo, x, x1, S, D, D);

    ln_kernel<<<S, 256, 0, stream>>>(x1, s2, b2n, y2);

    gemm_kernel<EPI_GELU><<<dim3(FF / 64, S / 64), blk, 0, stream>>>(y2, W1, b1, nullptr, hb, S, FF, D);

    gemm_kernel<EPI_RES><<<dim3(D / 64, S / 64), blk, 0, stream>>>(hb, W2, b2, x1, (float*)d_out, S, D, FF);
}

// Round 3
// 631.342 us; speedup vs baseline: 28.4641x; 28.4641x over previous
//
#include <hip/hip_runtime.h>
#include <hip/hip_bf16.h>
#include <math.h>

using bf16 = __hip_bfloat16;
typedef __attribute__((ext_vector_type(8))) short short8;
typedef __attribute__((ext_vector_type(4))) float f32x4;

constexpr int S = 4096, D = 1024, H = 16, HD = 64, FF = 4096;

static __device__ __forceinline__ float tof(bf16 v) { return __bfloat162float(v); }
static __device__ __forceinline__ bf16 tob(float v) { return __float2bfloat16(v); }

static __device__ __forceinline__ f32x4 mfma16(short8 a, short8 b, f32x4 c) {
    return __builtin_amdgcn_mfma_f32_16x16x32_bf16(a, b, c, 0, 0, 0);
}
// async global->LDS, 16B per lane; LDS dest = base + lane*16 (wave-uniform base)
static __device__ __forceinline__ void stage16(const bf16* g, bf16* l) {
    __builtin_amdgcn_global_load_lds((__attribute__((address_space(1))) void*)g,
                                     (__attribute__((address_space(3))) void*)l, 16, 0, 0);
}

// ---------------- LayerNorm: fp32 in -> bf16 out ----------------------------
__global__ __launch_bounds__(256) void ln_kernel(const float* __restrict__ x,
                                                 const float* __restrict__ scale,
                                                 const float* __restrict__ bias,
                                                 bf16* __restrict__ y) {
    int row = blockIdx.x, t = threadIdx.x;
    const float* xr = x + (size_t)row * D;
    float v[4], s = 0.f, ss = 0.f;
#pragma unroll
    for (int i = 0; i < 4; ++i) {
        v[i] = xr[t + 256 * i];
        s += v[i]; ss += v[i] * v[i];
    }
    __shared__ float r0[256], r1[256];
    r0[t] = s; r1[t] = ss;
    __syncthreads();
    for (int off = 128; off; off >>= 1) {
        if (t < off) { r0[t] += r0[t + off]; r1[t] += r1[t + off]; }
        __syncthreads();
    }
    float mu  = r0[0] * (1.f / D);
    float var = r1[0] * (1.f / D) - mu * mu;
    float inv = rsqrtf(var + 1e-6f);
    bf16* yr = y + (size_t)row * D;
#pragma unroll
    for (int i = 0; i < 4; ++i) {
        int c = t + 256 * i;
        yr[c] = tob((v[i] - mu) * inv * scale[c] + bias[c]);
    }
}

// ---------------- Weight transpose+convert: fp32 (K,N) -> bf16 (N,K) --------
__global__ __launch_bounds__(256) void wtrans(const float* __restrict__ W,
                                              bf16* __restrict__ BT, int K, int N) {
    __shared__ float t[32][33];
    int kt = blockIdx.y * 32, nt = blockIdx.x * 32;
    int tid = threadIdx.x, r = tid >> 5, c = tid & 31;
#pragma unroll
    for (int p = 0; p < 4; ++p)
        t[r + p * 8][c] = W[(size_t)(kt + r + p * 8) * N + nt + c];
    __syncthreads();
#pragma unroll
    for (int p = 0; p < 4; ++p)
        BT[(size_t)(nt + r + p * 8) * K + kt + c] = tob(t[c][r + p * 8]);
}

// ---------------- concat qkv biases -----------------------------------------
__global__ void bconcat(const float* __restrict__ bq, const float* __restrict__ bk,
                        const float* __restrict__ bv, float* __restrict__ out) {
    int i = blockIdx.x * 256 + threadIdx.x;  // 3072
    out[i] = i < 1024 ? bq[i] : (i < 2048 ? bk[i - 1024] : bv[i - 2048]);
}

// ---------------- MFMA GEMM: C[M,N] = A[M,K] * BT[N,K]^T + bias -------------
#define EPI_NONE 0  // bf16 out
#define EPI_RES  1  // fp32 out = acc + bias + resid(fp32)   (out may alias resid)
#define EPI_GELU 2  // bf16 out = gelu(acc + bias)

template <int EPI>
__global__ __launch_bounds__(256, 2) void gemm_bt(
    const bf16* __restrict__ A, const bf16* __restrict__ BT,
    const float* __restrict__ bias, const float* resid, void* out,
    int M, int N, int K) {
    __shared__ bf16 As[128 * 32];
    __shared__ bf16 Bs[128 * 32];
    const int tid = threadIdx.x;
    const int w = tid >> 6, lane = tid & 63;
    const int quad = lane >> 4, l16 = lane & 15;
    const int rowBase = blockIdx.y * 128, colBase = blockIdx.x * 128;
    const int wr = (w >> 1) * 64, wc = (w & 1) * 64;
    const int sr = lane >> 2, skb = (lane & 3) * 8;
    f32x4 acc[4][4] = {};
    for (int k0 = 0; k0 < K; k0 += 32) {
        __syncthreads();
#pragma unroll
        for (int t = 0; t < 2; ++t) {
            int inst = w * 2 + t;
            int r = inst * 16 + sr;
            stage16(A  + (size_t)(rowBase + r) * K + k0 + skb, As + inst * 512);
            stage16(BT + (size_t)(colBase + r) * K + k0 + skb, Bs + inst * 512);
        }
        __syncthreads();
        const bf16* pa = As + (wr + l16) * 32 + quad * 8;
        const bf16* pb = Bs + (wc + l16) * 32 + quad * 8;
        short8 a[4], b[4];
#pragma unroll
        for (int i = 0; i < 4; ++i) a[i] = *(const short8*)(pa + i * 512);
#pragma unroll
        for (int j = 0; j < 4; ++j) b[j] = *(const short8*)(pb + j * 512);
#pragma unroll
        for (int i = 0; i < 4; ++i)
#pragma unroll
            for (int j = 0; j < 4; ++j) acc[i][j] = mfma16(a[i], b[j], acc[i][j]);
    }
#pragma unroll
    for (int j = 0; j < 4; ++j) {
        int c = colBase + wc + j * 16 + l16;
        float bj = bias[c];
#pragma unroll
        for (int i = 0; i < 4; ++i) {
            int r0 = rowBase + wr + i * 16 + quad * 4;
#pragma unroll
            for (int reg = 0; reg < 4; ++reg) {
                size_t idx = (size_t)(r0 + reg) * N + c;
                float val = acc[i][j][reg] + bj;
                if (EPI == EPI_NONE) {
                    ((bf16*)out)[idx] = tob(val);
                } else if (EPI == EPI_RES) {
                    ((float*)out)[idx] = val + resid[idx];
                } else {
                    float g = 0.5f * val * (1.f + erff(val * 0.70710678118f));
                    ((bf16*)out)[idx] = tob(g);
                }
            }
        }
    }
}

// ---------------- RoPE on fused QKV (q scaled by 1/8 = 1/sqrt(HD)) ----------
__global__ __launch_bounds__(256) void rope_kernel(bf16* __restrict__ QKV) {
    int idx = blockIdx.x * 256 + threadIdx.x;  // S*H*32 pair slots
    int s = idx >> 9, rem = idx & 511, h = rem >> 5, c = rem & 31;
    float freq = __expf(-(float)c * (9.210340371976184f / 32.f));
    float ang = (float)s * freq, sn, cs;
    sincosf(ang, &sn, &cs);
    size_t base = (size_t)s * 3072 + h * 64 + c;
    float q1 = tof(QKV[base]), q2 = tof(QKV[base + 32]);
    QKV[base]      = tob((q1 * cs - q2 * sn) * 0.125f);
    QKV[base + 32] = tob((q2 * cs + q1 * sn) * 0.125f);
    float k1 = tof(QKV[base + 1024]), k2 = tof(QKV[base + 1056]);
    QKV[base + 1024] = tob(k1 * cs - k2 * sn);
    QKV[base + 1056] = tob(k2 * cs + k1 * sn);
}

// ---------------- V transpose (bit-level): QKV v-part -> VT[h][c][s] --------
__global__ __launch_bounds__(256) void vtrans(const short* __restrict__ QKV,
                                              short* __restrict__ VT) {
    int h = blockIdx.y, st = blockIdx.x * 64;
    __shared__ short t[64][72];
    int tid = threadIdx.x, r0 = tid >> 3, c0 = (tid & 7) * 8;
#pragma unroll
    for (int p = 0; p < 2; ++p) {
        int r = r0 + p * 32;
        short8 d = *(const short8*)(QKV + (size_t)(st + r) * 3072 + 2048 + h * 64 + c0);
#pragma unroll
        for (int j = 0; j < 8; ++j) t[r][c0 + j] = d[j];
    }
    __syncthreads();
#pragma unroll
    for (int p = 0; p < 2; ++p) {
        int c = r0 + p * 32;
        short8 v;
#pragma unroll
        for (int j = 0; j < 8; ++j) v[j] = t[c0 + j][c];
        *(short8*)(VT + ((size_t)h * 80 + c) * 4096 + st + c0) = v;
    }
}

// rows 64..79 of each head's VT: row 64 = 1.0 (l-accumulator column), rest 0
__global__ void vt_fill(short* __restrict__ VT) {
    int idx = blockIdx.x * 256 + threadIdx.x;  // 16 * 16 * 4096
    int h = idx >> 16, rem = idx & 65535, r = rem >> 12, s = rem & 4095;
    VT[((size_t)h * 80 + 64 + r) * 4096 + s] = (r == 0) ? (short)0x3F80 : (short)0;
}

// ---------------- Flash attention, MFMA, no-max softmax + ones-column l -----
// block = 4 waves; wave = 32 q-rows (2 tiles of 16); K-tile = 64 rows
__global__ __launch_bounds__(256, 2) void attn_kernel(const bf16* __restrict__ QKV,
                                                      const bf16* __restrict__ VT,
                                                      bf16* __restrict__ O) {
    const int h = blockIdx.x >> 5, qb = blockIdx.x & 31;
    const int w = threadIdx.x >> 6, lane = threadIdx.x & 63;
    const int quad = lane >> 4, l16 = lane & 15;
    const int q0 = qb * 128 + w * 32;
    const bf16* Qh = QKV + h * 64;
    const bf16* Kh = QKV + 1024 + h * 64;
    const bf16* Vh = VT + (size_t)h * 80 * 4096;
    __shared__ bf16 P[4][2][1024];  // [wave][qtile][16 rows x 64 cols]
    short8 qf[2][2];
#pragma unroll
    for (int qt = 0; qt < 2; ++qt)
#pragma unroll
        for (int c = 0; c < 2; ++c)
            qf[qt][c] = *(const short8*)(Qh + (size_t)(q0 + qt * 16 + l16) * 3072 + c * 32 + quad * 8);
    f32x4 acc[2][5] = {};
    const f32x4 zero = {0.f, 0.f, 0.f, 0.f};
    for (int kt = 0; kt < 4096; kt += 64) {
        // S = Q K^T  (scale already folded into q)
        f32x4 s[2][4];
#pragma unroll
        for (int nt = 0; nt < 4; ++nt) {
            const bf16* kr = Kh + (size_t)(kt + nt * 16 + l16) * 3072 + quad * 8;
            short8 kf0 = *(const short8*)(kr);
            short8 kf1 = *(const short8*)(kr + 32);
#pragma unroll
            for (int qt = 0; qt < 2; ++qt)
                s[qt][nt] = mfma16(qf[qt][1], kf1, mfma16(qf[qt][0], kf0, zero));
        }
        // P = exp(S) -> LDS (C-layout -> A-layout roundtrip)
#pragma unroll
        for (int qt = 0; qt < 2; ++qt)
#pragma unroll
            for (int nt = 0; nt < 4; ++nt)
#pragma unroll
                for (int r = 0; r < 4; ++r)
                    P[w][qt][(quad * 4 + r) * 64 + nt * 16 + l16] = tob(__expf(s[qt][nt][r]));
        asm volatile("s_waitcnt lgkmcnt(0)" ::: "memory");
        short8 pa[2][2];
#pragma unroll
        for (int qt = 0; qt < 2; ++qt)
#pragma unroll
            for (int c = 0; c < 2; ++c)
                pa[qt][c] = *(const short8*)(&P[w][qt][l16 * 64 + c * 32 + quad * 8]);
        // O += P V   (vt=4 is the ones-column -> l)
#pragma unroll
        for (int vt = 0; vt < 5; ++vt) {
            const bf16* vr = Vh + (size_t)(vt * 16 + l16) * 4096 + kt + quad * 8;
            short8 vf0 = *(const short8*)(vr);
            short8 vf1 = *(const short8*)(vr + 32);
#pragma unroll
            for (int qt = 0; qt < 2; ++qt)
                acc[qt][vt] = mfma16(pa[qt][1], vf1, mfma16(pa[qt][0], vf0, acc[qt][vt]));
        }
    }
#pragma unroll
    for (int qt = 0; qt < 2; ++qt) {
        float lr[4];
#pragma unroll
        for (int reg = 0; reg < 4; ++reg)
            lr[reg] = __shfl(acc[qt][4][reg], (threadIdx.x & 48), 64);
#pragma unroll
        for (int vt = 0; vt < 4; ++vt)
#pragma unroll
            for (int reg = 0; reg < 4; ++reg)
                O[(size_t)(q0 + qt * 16 + quad * 4 + reg) * 1024 + h * 64 + vt * 16 + l16] =
                    tob(acc[qt][vt][reg] / lr[reg]);
    }
}

extern "C" void kernel_launch(void* const* d_in, const int* in_sizes, int n_in,
                              void* d_out, int out_size, void* d_ws, size_t ws_size,
                              hipStream_t stream) {
    const float* x   = (const float*)d_in[0];
    const float* s1  = (const float*)d_in[1];
    const float* b1n = (const float*)d_in[2];
    const float* s2  = (const float*)d_in[3];
    const float* b2n = (const float*)d_in[4];
    const float* Wq  = (const float*)d_in[5];
    const float* bq  = (const float*)d_in[6];
    const float* Wk  = (const float*)d_in[7];
    const float* bk  = (const float*)d_in[8];
    const float* Wv  = (const float*)d_in[9];
    const float* bv  = (const float*)d_in[10];
    const float* Wo  = (const float*)d_in[11];
    const float* bo  = (const float*)d_in[12];
    const float* W1  = (const float*)d_in[13];
    const float* b1  = (const float*)d_in[14];
    const float* W2  = (const float*)d_in[15];
    const float* b2  = (const float*)d_in[16];

    char* ws = (char*)d_ws;
    bf16*  y     = (bf16*)(ws);                    // 8 MiB: ln1 out; later ln2 out; later BT2
    bf16*  QKV   = (bf16*)(ws + (8ull  << 20));    // 24 MiB
    bf16*  o     = (bf16*)(ws + (32ull << 20));    // 8 MiB
    bf16*  hb    = (bf16*)(ws + (40ull << 20));    // 32 MiB (FFN hidden)
    bf16*  BTqkv = (bf16*)(ws + (40ull << 20));    // 6 MiB  (aliases hb; dead before FFN1)
    bf16*  BTo   = (bf16*)(ws + (46ull << 20));    // 2 MiB  (aliases hb; dead before FFN1)
    bf16*  VT    = (bf16*)(ws + (72ull << 20));    // 10 MiB
    bf16*  BT1   = (bf16*)(ws + (82ull << 20));    // 8 MiB
    float* bqkv  = (float*)(ws + (90ull << 20));   // 12 KiB
    bf16*  BT2   = y;                              // written after FFN1 (y dead)
    float* x1    = (float*)d_out;                  // fp32 residual lives in d_out

    // weight transposes (fp32 KxN -> bf16 NxK)
    wtrans<<<dim3(32, 32),  256, 0, stream>>>(Wq, BTqkv,               D, D);
    wtrans<<<dim3(32, 32),  256, 0, stream>>>(Wk, BTqkv + 1024 * 1024, D, D);
    wtrans<<<dim3(32, 32),  256, 0, stream>>>(Wv, BTqkv + 2048 * 1024, D, D);
    wtrans<<<dim3(32, 32),  256, 0, stream>>>(Wo, BTo, D, D);
    wtrans<<<dim3(128, 32), 256, 0, stream>>>(W1, BT1, D, FF);
    bconcat<<<12, 256, 0, stream>>>(bq, bk, bv, bqkv);

    ln_kernel<<<S, 256, 0, stream>>>(x, s1, b1n, y);

    // fused QKV GEMM: (4096 x 3072)
    gemm_bt<EPI_NONE><<<dim3(24, 32), 256, 0, stream>>>(y, BTqkv, bqkv, nullptr, QKV, S, 3072, D);

    rope_kernel<<<(S * H * 32) / 256, 256, 0, stream>>>(QKV);
    vtrans<<<dim3(64, 16), 256, 0, stream>>>((const short*)QKV, (short*)VT);
    vt_fill<<<4096, 256, 0, stream>>>((short*)VT);

    attn_kernel<<<H * 32, 256, 0, stream>>>(QKV, VT, o);

    // O projection + residual (fp32) -> x1 (= d_out)
    gemm_bt<EPI_RES><<<dim3(8, 32), 256, 0, stream>>>(o, BTo, bo, x, x1, S, D, D);

    ln_kernel<<<S, 256, 0, stream>>>(x1, s2, b2n, y);

    // FFN1 + GELU
    gemm_bt<EPI_GELU><<<dim3(32, 32), 256, 0, stream>>>(y, BT1, b1, nullptr, hb, S, FF, D);

    // W2 transpose now (y is dead), then FFN2 + residual (in-place on d_out)
    wtrans<<<dim3(32, 128), 256, 0, stream>>>(W2, BT2, FF, D);
    gemm_bt<EPI_RES><<<dim3(8, 32), 256, 0, stream>>>(hb, BT2, b2, x1, d_out, S, D, FF);
}

// Round 4
// 611.423 us; speedup vs baseline: 29.3914x; 1.0326x over previous
//
#include <hip/hip_runtime.h>
#include <hip/hip_bf16.h>
#include <math.h>

using bf16 = __hip_bfloat16;
typedef __attribute__((ext_vector_type(8))) short short8;
typedef __attribute__((ext_vector_type(4))) short s16x4;
typedef __attribute__((ext_vector_type(4))) float f32x4;

constexpr int S = 4096, D = 1024, H = 16, HD = 64, FF = 4096;

static __device__ __forceinline__ float tof(bf16 v) { return __bfloat162float(v); }
static __device__ __forceinline__ bf16 tob(float v) { return __float2bfloat16(v); }
static __device__ __forceinline__ short tobs(float v) {
    bf16 h = __float2bfloat16(v);
    return *reinterpret_cast<short*>(&h);
}

static __device__ __forceinline__ f32x4 mfma16(short8 a, short8 b, f32x4 c) {
    return __builtin_amdgcn_mfma_f32_16x16x32_bf16(a, b, c, 0, 0, 0);
}
// async global->LDS, 16B per lane; LDS dest = wave-uniform base + lane*16
static __device__ __forceinline__ void stage16(const bf16* g, bf16* l) {
    __builtin_amdgcn_global_load_lds((__attribute__((address_space(1))) void*)g,
                                     (__attribute__((address_space(3))) void*)l, 16, 0, 0);
}

// ---------------- LayerNorm: fp32 in -> bf16 out ----------------------------
__global__ __launch_bounds__(256) void ln_kernel(const float* __restrict__ x,
                                                 const float* __restrict__ scale,
                                                 const float* __restrict__ bias,
                                                 bf16* __restrict__ y) {
    int row = blockIdx.x, t = threadIdx.x;
    const float* xr = x + (size_t)row * D;
    float v[4], s = 0.f, ss = 0.f;
#pragma unroll
    for (int i = 0; i < 4; ++i) {
        v[i] = xr[t + 256 * i];
        s += v[i]; ss += v[i] * v[i];
    }
    __shared__ float r0[256], r1[256];
    r0[t] = s; r1[t] = ss;
    __syncthreads();
    for (int off = 128; off; off >>= 1) {
        if (t < off) { r0[t] += r0[t + off]; r1[t] += r1[t + off]; }
        __syncthreads();
    }
    float mu  = r0[0] * (1.f / D);
    float var = r1[0] * (1.f / D) - mu * mu;
    float inv = rsqrtf(var + 1e-6f);
    bf16* yr = y + (size_t)row * D;
#pragma unroll
    for (int i = 0; i < 4; ++i) {
        int c = t + 256 * i;
        yr[c] = tob((v[i] - mu) * inv * scale[c] + bias[c]);
    }
}

// ---------------- Weight transpose+convert: fp32 (K,N) -> bf16 (N,K) --------
__global__ __launch_bounds__(256) void wtrans(const float* __restrict__ W,
                                              bf16* __restrict__ BT, int K, int N) {
    __shared__ float t[32][33];
    int kt = blockIdx.y * 32, nt = blockIdx.x * 32;
    int tid = threadIdx.x, r = tid >> 5, c = tid & 31;
#pragma unroll
    for (int p = 0; p < 4; ++p)
        t[r + p * 8][c] = W[(size_t)(kt + r + p * 8) * N + nt + c];
    __syncthreads();
#pragma unroll
    for (int p = 0; p < 4; ++p)
        BT[(size_t)(nt + r + p * 8) * K + kt + c] = tob(t[c][r + p * 8]);
}

// ---------------- concat qkv biases -----------------------------------------
__global__ void bconcat(const float* __restrict__ bq, const float* __restrict__ bk,
                        const float* __restrict__ bv, float* __restrict__ out) {
    int i = blockIdx.x * 256 + threadIdx.x;  // 3072
    out[i] = i < 1024 ? bq[i] : (i < 2048 ? bk[i - 1024] : bv[i - 2048]);
}

// ---------------- MFMA GEMM: C[M,N] = A[M,K] * BT[N,K]^T + bias -------------
#define EPI_NONE 0  // bf16 out
#define EPI_RES  1  // fp32 out = acc + bias + resid(fp32)   (out may alias resid)
#define EPI_GELU 2  // bf16 out = gelu(acc + bias)

template <int EPI>
__global__ __launch_bounds__(256, 2) void gemm_bt(
    const bf16* __restrict__ A, const bf16* __restrict__ BT,
    const float* __restrict__ bias, const float* resid, void* out,
    int M, int N, int K) {
    __shared__ bf16 As[128 * 32];
    __shared__ bf16 Bs[128 * 32];
    const int tid = threadIdx.x;
    const int w = tid >> 6, lane = tid & 63;
    const int quad = lane >> 4, l16 = lane & 15;
    const int rowBase = blockIdx.y * 128, colBase = blockIdx.x * 128;
    const int wr = (w >> 1) * 64, wc = (w & 1) * 64;
    const int sr = lane >> 2, skb = (lane & 3) * 8;
    f32x4 acc[4][4] = {};
    for (int k0 = 0; k0 < K; k0 += 32) {
        __syncthreads();
#pragma unroll
        for (int t = 0; t < 2; ++t) {
            int inst = w * 2 + t;
            int r = inst * 16 + sr;
            stage16(A  + (size_t)(rowBase + r) * K + k0 + skb, As + inst * 512);
            stage16(BT + (size_t)(colBase + r) * K + k0 + skb, Bs + inst * 512);
        }
        __syncthreads();
        const bf16* pa = As + (wr + l16) * 32 + quad * 8;
        const bf16* pb = Bs + (wc + l16) * 32 + quad * 8;
        short8 a[4], b[4];
#pragma unroll
        for (int i = 0; i < 4; ++i) a[i] = *(const short8*)(pa + i * 512);
#pragma unroll
        for (int j = 0; j < 4; ++j) b[j] = *(const short8*)(pb + j * 512);
#pragma unroll
        for (int i = 0; i < 4; ++i)
#pragma unroll
            for (int j = 0; j < 4; ++j) acc[i][j] = mfma16(a[i], b[j], acc[i][j]);
    }
#pragma unroll
    for (int j = 0; j < 4; ++j) {
        int c = colBase + wc + j * 16 + l16;
        float bj = bias[c];
#pragma unroll
        for (int i = 0; i < 4; ++i) {
            int r0 = rowBase + wr + i * 16 + quad * 4;
#pragma unroll
            for (int reg = 0; reg < 4; ++reg) {
                size_t idx = (size_t)(r0 + reg) * N + c;
                float val = acc[i][j][reg] + bj;
                if (EPI == EPI_NONE) {
                    ((bf16*)out)[idx] = tob(val);
                } else if (EPI == EPI_RES) {
                    ((float*)out)[idx] = val + resid[idx];
                } else {
                    float g = 0.5f * val * (1.f + erff(val * 0.70710678118f));
                    ((bf16*)out)[idx] = tob(g);
                }
            }
        }
    }
}

// ---------------- RoPE on fused QKV (q scaled by 1/8 = 1/sqrt(HD)) ----------
__global__ __launch_bounds__(256) void rope_kernel(bf16* __restrict__ QKV) {
    int idx = blockIdx.x * 256 + threadIdx.x;  // S*H*32 pair slots
    int s = idx >> 9, rem = idx & 511, h = rem >> 5, c = rem & 31;
    float freq = __expf(-(float)c * (9.210340371976184f / 32.f));
    float ang = (float)s * freq, sn, cs;
    sincosf(ang, &sn, &cs);
    size_t base = (size_t)s * 3072 + h * 64 + c;
    float q1 = tof(QKV[base]), q2 = tof(QKV[base + 32]);
    QKV[base]      = tob((q1 * cs - q2 * sn) * 0.125f);
    QKV[base + 32] = tob((q2 * cs + q1 * sn) * 0.125f);
    float k1 = tof(QKV[base + 1024]), k2 = tof(QKV[base + 1056]);
    QKV[base + 1024] = tob(k1 * cs - k2 * sn);
    QKV[base + 1056] = tob(k2 * cs + k1 * sn);
}

// ---------------- V transpose: QKV v-part -> VT[h][c][s], 64 rows/head ------
__global__ __launch_bounds__(256) void vtrans(const short* __restrict__ QKV,
                                              short* __restrict__ VT) {
    int h = blockIdx.y, st = blockIdx.x * 64;
    __shared__ short t[64][72];
    int tid = threadIdx.x, r0 = tid >> 3, c0 = (tid & 7) * 8;
#pragma unroll
    for (int p = 0; p < 2; ++p) {
        int r = r0 + p * 32;
        short8 d = *(const short8*)(QKV + (size_t)(st + r) * 3072 + 2048 + h * 64 + c0);
#pragma unroll
        for (int j = 0; j < 8; ++j) t[r][c0 + j] = d[j];
    }
    __syncthreads();
#pragma unroll
    for (int p = 0; p < 2; ++p) {
        int c = r0 + p * 32;
        short8 v;
#pragma unroll
        for (int j = 0; j < 8; ++j) v[j] = t[c0 + j][c];
        *(short8*)(VT + ((size_t)h * 64 + c) * 4096 + st + c0) = v;
    }
}

// ---------------- Flash attention v2: S^T form, swizzled P^T, kt-split-2 ----
// block = 4 waves over 64 q-rows: wave w: qhalf=w&1 (32 rows), kthalf=w>>1.
// Wave computes S^T = K*Q^T (keys on C-rows -> contiguous P^T packing),
// P^T via XOR-swizzled wave-private LDS, PV as O^T = V^T * P^T. l in-register.
__global__ __launch_bounds__(256, 2) void attn_kernel(const bf16* __restrict__ QKV,
                                                      const bf16* __restrict__ VT,
                                                      bf16* __restrict__ O) {
    const int h = blockIdx.x >> 6, qb = blockIdx.x & 63;
    const int w = threadIdx.x >> 6, lane = threadIdx.x & 63;
    const int quad = lane >> 4, l16 = lane & 15;
    const int qhalf = w & 1, kthalf = w >> 1;
    const int q0 = qb * 64 + qhalf * 32;
    const bf16* Qh = QKV + h * 64;
    const bf16* Kh = QKV + 1024 + h * 64;
    const bf16* Vh = VT + (size_t)h * 64 * 4096;
    __shared__ bf16 Pbuf[4][2048];      // per-wave P^T: 32 q x 64 keys (4 KiB)
    __shared__ float Macc[2][32 * 64];  // merge: per q-half partial O^T
    __shared__ float Ml[2][32];
    const int sw = l16 & 7;  // XOR swizzle key (row-derived)

    // Q frags (loop-invariant): B-operand layout n=l16 (q), k=quad*8+j (hd)
    short8 qf[2][2];
#pragma unroll
    for (int qt = 0; qt < 2; ++qt)
#pragma unroll
        for (int c = 0; c < 2; ++c)
            qf[qt][c] = *(const short8*)(Qh + (size_t)(q0 + qt * 16 + l16) * 3072 + c * 32 + quad * 8);

    f32x4 acc[4][2] = {};
    float lac[2] = {0.f, 0.f};
    const f32x4 zero = {0.f, 0.f, 0.f, 0.f};
    bf16* P = Pbuf[w];

    const int ktBeg = kthalf * 2048, ktEnd = ktBeg + 2048;
    for (int kt = ktBeg; kt < ktEnd; kt += 64) {
        // S^T tiles: A = K rows (m=key), B = Q (n=q)
        f32x4 st[4][2];
#pragma unroll
        for (int nt = 0; nt < 4; ++nt) {
            const bf16* kr = Kh + (size_t)(kt + nt * 16 + l16) * 3072 + quad * 8;
            short8 k0 = *(const short8*)(kr);
            short8 k1 = *(const short8*)(kr + 32);
#pragma unroll
            for (int qt = 0; qt < 2; ++qt)
                st[nt][qt] = mfma16(k1, qf[qt][1], mfma16(k0, qf[qt][0], zero));
        }
        // P^T = exp(S^T): lane holds keys nt*16+quad*4+{0..3} of q=qt*16+l16
#pragma unroll
        for (int nt = 0; nt < 4; ++nt)
#pragma unroll
            for (int qt = 0; qt < 2; ++qt) {
                float e0 = __expf(st[nt][qt][0]), e1 = __expf(st[nt][qt][1]);
                float e2 = __expf(st[nt][qt][2]), e3 = __expf(st[nt][qt][3]);
                lac[qt] += (e0 + e1) + (e2 + e3);
                s16x4 pk = {tobs(e0), tobs(e1), tobs(e2), tobs(e3)};
                // row q, logical chunk nt*2+(quad>>1), half quad&1, XOR-swizzled
                *(s16x4*)(P + (qt * 16 + l16) * 64 +
                          (((nt * 2 + (quad >> 1)) ^ sw) * 8) + (quad & 1) * 4) = pk;
            }
        asm volatile("s_waitcnt lgkmcnt(0)" ::: "memory");
        // PV: A = V^T (m=vdim), B = P^T (n=q, k=key)
#pragma unroll
        for (int c = 0; c < 2; ++c) {
            short8 pB[2];
#pragma unroll
            for (int qt = 0; qt < 2; ++qt)
                pB[qt] = *(const short8*)(P + (qt * 16 + l16) * 64 + (((c * 4 + quad) ^ sw) * 8));
#pragma unroll
            for (int vt = 0; vt < 4; ++vt) {
                short8 vf = *(const short8*)(Vh + (size_t)(vt * 16 + l16) * 4096 + kt + c * 32 + quad * 8);
#pragma unroll
                for (int qt = 0; qt < 2; ++qt)
                    acc[vt][qt] = mfma16(vf, pB[qt], acc[vt][qt]);
            }
        }
    }
    // full l over this kt-half: reduce over quads (lane bits 4,5)
#pragma unroll
    for (int qt = 0; qt < 2; ++qt) {
        lac[qt] += __shfl_xor(lac[qt], 16, 64);
        lac[qt] += __shfl_xor(lac[qt], 32, 64);
    }
    // merge kt halves through LDS
    if (kthalf == 1) {
        float* M = Macc[qhalf];
#pragma unroll
        for (int qt = 0; qt < 2; ++qt)
#pragma unroll
            for (int vt = 0; vt < 4; ++vt)
                *(f32x4*)(M + (qt * 16 + l16) * 64 + vt * 16 + quad * 4) = acc[vt][qt];
        if (quad == 0) {
            Ml[qhalf][l16]      = lac[0];
            Ml[qhalf][16 + l16] = lac[1];
        }
    }
    __syncthreads();
    if (kthalf == 0) {
        const float* M = Macc[qhalf];
#pragma unroll
        for (int qt = 0; qt < 2; ++qt) {
            float linv = 1.f / (lac[qt] + Ml[qhalf][qt * 16 + l16]);
#pragma unroll
            for (int vt = 0; vt < 4; ++vt) {
                f32x4 ap = *(const f32x4*)(M + (qt * 16 + l16) * 64 + vt * 16 + quad * 4);
                s16x4 ov = {tobs((acc[vt][qt][0] + ap[0]) * linv),
                            tobs((acc[vt][qt][1] + ap[1]) * linv),
                            tobs((acc[vt][qt][2] + ap[2]) * linv),
                            tobs((acc[vt][qt][3] + ap[3]) * linv)};
                *(s16x4*)(O + (size_t)(q0 + qt * 16 + l16) * 1024 + h * 64 + vt * 16 + quad * 4) = ov;
            }
        }
    }
}

extern "C" void kernel_launch(void* const* d_in, const int* in_sizes, int n_in,
                              void* d_out, int out_size, void* d_ws, size_t ws_size,
                              hipStream_t stream) {
    const float* x   = (const float*)d_in[0];
    const float* s1  = (const float*)d_in[1];
    const float* b1n = (const float*)d_in[2];
    const float* s2  = (const float*)d_in[3];
    const float* b2n = (const float*)d_in[4];
    const float* Wq  = (const float*)d_in[5];
    const float* bq  = (const float*)d_in[6];
    const float* Wk  = (const float*)d_in[7];
    const float* bk  = (const float*)d_in[8];
    const float* Wv  = (const float*)d_in[9];
    const float* bv  = (const float*)d_in[10];
    const float* Wo  = (const float*)d_in[11];
    const float* bo  = (const float*)d_in[12];
    const float* W1  = (const float*)d_in[13];
    const float* b1  = (const float*)d_in[14];
    const float* W2  = (const float*)d_in[15];
    const float* b2  = (const float*)d_in[16];

    char* ws = (char*)d_ws;
    bf16*  y     = (bf16*)(ws);                    // 8 MiB: ln1 out; later ln2 out; later BT2
    bf16*  QKV   = (bf16*)(ws + (8ull  << 20));    // 24 MiB
    bf16*  o     = (bf16*)(ws + (32ull << 20));    // 8 MiB
    bf16*  hb    = (bf16*)(ws + (40ull << 20));    // 32 MiB (FFN hidden)
    bf16*  BTqkv = (bf16*)(ws + (40ull << 20));    // 6 MiB  (aliases hb; dead before FFN1)
    bf16*  BTo   = (bf16*)(ws + (46ull << 20));    // 2 MiB  (aliases hb; dead before FFN1)
    bf16*  VT    = (bf16*)(ws + (72ull << 20));    // 8 MiB
    bf16*  BT1   = (bf16*)(ws + (82ull << 20));    // 8 MiB
    float* bqkv  = (float*)(ws + (90ull << 20));   // 12 KiB
    bf16*  BT2   = y;                              // written after FFN1 (y dead)
    float* x1    = (float*)d_out;                  // fp32 residual lives in d_out

    // weight transposes (fp32 KxN -> bf16 NxK)
    wtrans<<<dim3(32, 32),  256, 0, stream>>>(Wq, BTqkv,               D, D);
    wtrans<<<dim3(32, 32),  256, 0, stream>>>(Wk, BTqkv + 1024 * 1024, D, D);
    wtrans<<<dim3(32, 32),  256, 0, stream>>>(Wv, BTqkv + 2048 * 1024, D, D);
    wtrans<<<dim3(32, 32),  256, 0, stream>>>(Wo, BTo, D, D);
    wtrans<<<dim3(128, 32), 256, 0, stream>>>(W1, BT1, D, FF);
    bconcat<<<12, 256, 0, stream>>>(bq, bk, bv, bqkv);

    ln_kernel<<<S, 256, 0, stream>>>(x, s1, b1n, y);

    // fused QKV GEMM: (4096 x 3072)
    gemm_bt<EPI_NONE><<<dim3(24, 32), 256, 0, stream>>>(y, BTqkv, bqkv, nullptr, QKV, S, 3072, D);

    rope_kernel<<<(S * H * 32) / 256, 256, 0, stream>>>(QKV);
    vtrans<<<dim3(64, 16), 256, 0, stream>>>((const short*)QKV, (short*)VT);

    attn_kernel<<<H * 64, 256, 0, stream>>>(QKV, VT, o);

    // O projection + residual (fp32) -> x1 (= d_out)
    gemm_bt<EPI_RES><<<dim3(8, 32), 256, 0, stream>>>(o, BTo, bo, x, x1, S, D, D);

    ln_kernel<<<S, 256, 0, stream>>>(x1, s2, b2n, y);

    // FFN1 + GELU
    gemm_bt<EPI_GELU><<<dim3(32, 32), 256, 0, stream>>>(y, BT1, b1, nullptr, hb, S, FF, D);

    // W2 transpose now (y is dead), then FFN2 + residual (in-place on d_out)
    wtrans<<<dim3(32, 128), 256, 0, stream>>>(W2, BT2, FF, D);
    gemm_bt<EPI_RES><<<dim3(8, 32), 256, 0, stream>>>(hb, BT2, b2, x1, d_out, S, D, FF);
}

// Round 5
// 495.141 us; speedup vs baseline: 36.2940x; 1.2348x over previous
//
#include <hip/hip_runtime.h>
#include <hip/hip_bf16.h>
#include <math.h>

using bf16 = __hip_bfloat16;
typedef __attribute__((ext_vector_type(8))) short short8;
typedef __attribute__((ext_vector_type(4))) short s16x4;
typedef __attribute__((ext_vector_type(4))) float f32x4;

constexpr int S = 4096, D = 1024, H = 16, HD = 64, FF = 4096;

static __device__ __forceinline__ float tof(bf16 v) { return __bfloat162float(v); }
static __device__ __forceinline__ bf16 tob(float v) { return __float2bfloat16(v); }
static __device__ __forceinline__ short tobs(float v) {
    bf16 h = __float2bfloat16(v);
    return *reinterpret_cast<short*>(&h);
}

static __device__ __forceinline__ f32x4 mfma16(short8 a, short8 b, f32x4 c) {
    return __builtin_amdgcn_mfma_f32_16x16x32_bf16(a, b, c, 0, 0, 0);
}
// async global->LDS, 16B per lane; LDS dest = wave-uniform base + lane*16
static __device__ __forceinline__ void stage16(const bf16* g, bf16* l) {
    __builtin_amdgcn_global_load_lds((__attribute__((address_space(1))) void*)g,
                                     (__attribute__((address_space(3))) void*)l, 16, 0, 0);
}

// ---------------- LayerNorm: fp32 in -> bf16 out ----------------------------
__global__ __launch_bounds__(256) void ln_kernel(const float* __restrict__ x,
                                                 const float* __restrict__ scale,
                                                 const float* __restrict__ bias,
                                                 bf16* __restrict__ y) {
    int row = blockIdx.x, t = threadIdx.x;
    const float* xr = x + (size_t)row * D;
    float v[4], s = 0.f, ss = 0.f;
#pragma unroll
    for (int i = 0; i < 4; ++i) {
        v[i] = xr[t + 256 * i];
        s += v[i]; ss += v[i] * v[i];
    }
    __shared__ float r0[256], r1[256];
    r0[t] = s; r1[t] = ss;
    __syncthreads();
    for (int off = 128; off; off >>= 1) {
        if (t < off) { r0[t] += r0[t + off]; r1[t] += r1[t + off]; }
        __syncthreads();
    }
    float mu  = r0[0] * (1.f / D);
    float var = r1[0] * (1.f / D) - mu * mu;
    float inv = rsqrtf(var + 1e-6f);
    bf16* yr = y + (size_t)row * D;
#pragma unroll
    for (int i = 0; i < 4; ++i) {
        int c = t + 256 * i;
        yr[c] = tob((v[i] - mu) * inv * scale[c] + bias[c]);
    }
}

// ---------------- Weight transpose+convert: fp32 (K,N) -> bf16 (N,K) --------
__global__ __launch_bounds__(256) void wtrans(const float* __restrict__ W,
                                              bf16* __restrict__ BT, int K, int N) {
    __shared__ float t[32][33];
    int kt = blockIdx.y * 32, nt = blockIdx.x * 32;
    int tid = threadIdx.x, r = tid >> 5, c = tid & 31;
#pragma unroll
    for (int p = 0; p < 4; ++p)
        t[r + p * 8][c] = W[(size_t)(kt + r + p * 8) * N + nt + c];
    __syncthreads();
#pragma unroll
    for (int p = 0; p < 4; ++p)
        BT[(size_t)(nt + r + p * 8) * K + kt + c] = tob(t[c][r + p * 8]);
}

// ---------------- concat qkv biases -----------------------------------------
__global__ void bconcat(const float* __restrict__ bq, const float* __restrict__ bk,
                        const float* __restrict__ bv, float* __restrict__ out) {
    int i = blockIdx.x * 256 + threadIdx.x;  // 3072
    out[i] = i < 1024 ? bq[i] : (i < 2048 ? bk[i - 1024] : bv[i - 2048]);
}

// ---------------- MFMA GEMM: C[M,N] = A[M,K] * BT[N,K]^T + bias -------------
#define EPI_NONE 0  // bf16 out
#define EPI_RES  1  // fp32 out = acc + bias + resid(fp32)   (out may alias resid)
#define EPI_GELU 2  // bf16 out = gelu(acc + bias)

template <int EPI>
__global__ __launch_bounds__(256, 2) void gemm_bt(
    const bf16* __restrict__ A, const bf16* __restrict__ BT,
    const float* __restrict__ bias, const float* resid, void* out,
    int M, int N, int K) {
    __shared__ bf16 As[128 * 32];
    __shared__ bf16 Bs[128 * 32];
    const int tid = threadIdx.x;
    const int w = tid >> 6, lane = tid & 63;
    const int quad = lane >> 4, l16 = lane & 15;
    const int rowBase = blockIdx.y * 128, colBase = blockIdx.x * 128;
    const int wr = (w >> 1) * 64, wc = (w & 1) * 64;
    const int sr = lane >> 2, skb = (lane & 3) * 8;
    f32x4 acc[4][4] = {};
    for (int k0 = 0; k0 < K; k0 += 32) {
        __syncthreads();
#pragma unroll
        for (int t = 0; t < 2; ++t) {
            int inst = w * 2 + t;
            int r = inst * 16 + sr;
            stage16(A  + (size_t)(rowBase + r) * K + k0 + skb, As + inst * 512);
            stage16(BT + (size_t)(colBase + r) * K + k0 + skb, Bs + inst * 512);
        }
        __syncthreads();
        const bf16* pa = As + (wr + l16) * 32 + quad * 8;
        const bf16* pb = Bs + (wc + l16) * 32 + quad * 8;
        short8 a[4], b[4];
#pragma unroll
        for (int i = 0; i < 4; ++i) a[i] = *(const short8*)(pa + i * 512);
#pragma unroll
        for (int j = 0; j < 4; ++j) b[j] = *(const short8*)(pb + j * 512);
#pragma unroll
        for (int i = 0; i < 4; ++i)
#pragma unroll
            for (int j = 0; j < 4; ++j) acc[i][j] = mfma16(a[i], b[j], acc[i][j]);
    }
#pragma unroll
    for (int j = 0; j < 4; ++j) {
        int c = colBase + wc + j * 16 + l16;
        float bj = bias[c];
#pragma unroll
        for (int i = 0; i < 4; ++i) {
            int r0 = rowBase + wr + i * 16 + quad * 4;
#pragma unroll
            for (int reg = 0; reg < 4; ++reg) {
                size_t idx = (size_t)(r0 + reg) * N + c;
                float val = acc[i][j][reg] + bj;
                if (EPI == EPI_NONE) {
                    ((bf16*)out)[idx] = tob(val);
                } else if (EPI == EPI_RES) {
                    ((float*)out)[idx] = val + resid[idx];
                } else {
                    float g = 0.5f * val * (1.f + erff(val * 0.70710678118f));
                    ((bf16*)out)[idx] = tob(g);
                }
            }
        }
    }
}

// ---------------- RoPE on fused QKV -----------------------------------------
// q scaled by (1/sqrt(HD)) * log2(e) so attention can use exp2 directly.
__global__ __launch_bounds__(256) void rope_kernel(bf16* __restrict__ QKV) {
    int idx = blockIdx.x * 256 + threadIdx.x;  // S*H*32 pair slots
    int s = idx >> 9, rem = idx & 511, h = rem >> 5, c = rem & 31;
    float freq = __expf(-(float)c * (9.210340371976184f / 32.f));
    float ang = (float)s * freq, sn, cs;
    sincosf(ang, &sn, &cs);
    const float qs = 0.125f * 1.44269504088896f;
    size_t base = (size_t)s * 3072 + h * 64 + c;
    float q1 = tof(QKV[base]), q2 = tof(QKV[base + 32]);
    QKV[base]      = tob((q1 * cs - q2 * sn) * qs);
    QKV[base + 32] = tob((q2 * cs + q1 * sn) * qs);
    float k1 = tof(QKV[base + 1024]), k2 = tof(QKV[base + 1056]);
    QKV[base + 1024] = tob(k1 * cs - k2 * sn);
    QKV[base + 1056] = tob(k2 * cs + k1 * sn);
}

// ---------------- V transpose: QKV v-part -> VT[h][c][s], 64 rows/head ------
__global__ __launch_bounds__(256) void vtrans(const short* __restrict__ QKV,
                                              short* __restrict__ VT) {
    int h = blockIdx.y, st = blockIdx.x * 64;
    __shared__ short t[64][72];
    int tid = threadIdx.x, r0 = tid >> 3, c0 = (tid & 7) * 8;
#pragma unroll
    for (int p = 0; p < 2; ++p) {
        int r = r0 + p * 32;
        short8 d = *(const short8*)(QKV + (size_t)(st + r) * 3072 + 2048 + h * 64 + c0);
#pragma unroll
        for (int j = 0; j < 8; ++j) t[r][c0 + j] = d[j];
    }
    __syncthreads();
#pragma unroll
    for (int p = 0; p < 2; ++p) {
        int c = r0 + p * 32;
        short8 v;
#pragma unroll
        for (int j = 0; j < 8; ++j) v[j] = t[c0 + j][c];
        *(short8*)(VT + ((size_t)h * 64 + c) * 4096 + st + c0) = v;
    }
}

// ---------------- Flash attention v3: LDS-staged K/V tiles (m97 pattern) ----
// block = 4 waves over 64 q-rows: wave w: qhalf=w&1 (32 rows), kthalf=w>>1.
// Per iter each wave stages one 8-KB tile (K or V for its kt-half) via
// global_load_lds with XOR-chunk-swizzled source; frags via ds_read_b128.
__global__ __launch_bounds__(256, 3) void attn_kernel(const bf16* __restrict__ QKV,
                                                      const bf16* __restrict__ VT,
                                                      bf16* __restrict__ O) {
    const int h = blockIdx.x >> 6, qb = blockIdx.x & 63;
    const int w = threadIdx.x >> 6, lane = threadIdx.x & 63;
    const int quad = lane >> 4, l16 = lane & 15;
    const int qhalf = w & 1, kthalf = w >> 1;
    const int q0 = qb * 64 + qhalf * 32;
    const bf16* Qh = QKV + h * 64;
    const bf16* Kh = QKV + 1024 + h * 64;
    const bf16* Vh = VT + (size_t)h * 64 * 4096;

    // LDS layout (48.25 KiB -> 3 blocks/CU):
    //   [0,16K):   Ks[2][64*64]   (aliased by Macc[2][32*64] fp32 after loop)
    //   [16K,32K): Vs[2][64*64]
    //   [32K,48K): P[4][32*64]    (wave-private P^T)
    //   [48K,+256): Ml[2][32]
    __shared__ char smem[49408];
    bf16*  Ks   = (bf16*)(smem);
    bf16*  Vs   = (bf16*)(smem + 16384);
    bf16*  P    = (bf16*)(smem + 32768) + w * 2048;
    float* Macc = (float*)(smem);
    float* Ml   = (float*)(smem + 49152);

    const int sw = l16 & 7;                      // frag-read XOR swizzle key
    const int rloc = lane >> 3, slot = lane & 7; // staging: 8 lanes per row
    bf16* stDst = (w & 1 ? Vs : Ks) + kthalf * 4096;

    // Q frags (loop-invariant): B-operand n=l16 (q), k=quad*8+j (hd)
    short8 qf[2][2];
#pragma unroll
    for (int qt = 0; qt < 2; ++qt)
#pragma unroll
        for (int c = 0; c < 2; ++c)
            qf[qt][c] = *(const short8*)(Qh + (size_t)(q0 + qt * 16 + l16) * 3072 + c * 32 + quad * 8);

    f32x4 acc[4][2] = {};
    float lac[2] = {0.f, 0.f};
    const f32x4 zero = {0.f, 0.f, 0.f, 0.f};
    const bf16* Kt = Ks + kthalf * 4096;
    const bf16* Vt = Vs + kthalf * 4096;

    for (int kt = 0; kt < 2048; kt += 64) {
        const int ktA = kthalf * 2048 + kt;
        __syncthreads();  // prev iter's tile reads complete
        // stage my 8-KB tile: LDS[row][slot] = global chunk (slot^row&7)
#pragma unroll
        for (int is = 0; is < 8; ++is) {
            const bf16* src = (w & 1)
                ? Vh + (size_t)(is * 8 + rloc) * 4096 + ktA + (slot ^ rloc) * 8
                : Kh + (size_t)(ktA + is * 8 + rloc) * 3072 + (slot ^ rloc) * 8;
            stage16(src, stDst + is * 512);
        }
        __syncthreads();  // DMA drained (compiler emits vmcnt(0) before barrier)

        // S^T tiles: A = K rows (m=key), B = Q (n=q)
        f32x4 st[4][2];
#pragma unroll
        for (int nt = 0; nt < 4; ++nt) {
            short8 k0 = *(const short8*)(Kt + (nt * 16 + l16) * 64 + ((quad ^ sw) * 8));
            short8 k1 = *(const short8*)(Kt + (nt * 16 + l16) * 64 + (((quad + 4) ^ sw) * 8));
#pragma unroll
            for (int qt = 0; qt < 2; ++qt)
                st[nt][qt] = mfma16(k1, qf[qt][1], mfma16(k0, qf[qt][0], zero));
        }
        // P^T = exp2(S^T) (log2e folded into q scale)
#pragma unroll
        for (int nt = 0; nt < 4; ++nt)
#pragma unroll
            for (int qt = 0; qt < 2; ++qt) {
                float e0 = exp2f(st[nt][qt][0]), e1 = exp2f(st[nt][qt][1]);
                float e2 = exp2f(st[nt][qt][2]), e3 = exp2f(st[nt][qt][3]);
                lac[qt] += (e0 + e1) + (e2 + e3);
                s16x4 pk = {tobs(e0), tobs(e1), tobs(e2), tobs(e3)};
                *(s16x4*)(P + (qt * 16 + l16) * 64 +
                          (((nt * 2 + (quad >> 1)) ^ sw) * 8) + (quad & 1) * 4) = pk;
            }
        asm volatile("s_waitcnt lgkmcnt(0)" ::: "memory");
        // PV: A = V^T (m=vdim), B = P^T (n=q, k=key)
#pragma unroll
        for (int c = 0; c < 2; ++c) {
            short8 pB[2];
#pragma unroll
            for (int qt = 0; qt < 2; ++qt)
                pB[qt] = *(const short8*)(P + (qt * 16 + l16) * 64 + (((c * 4 + quad) ^ sw) * 8));
#pragma unroll
            for (int vt = 0; vt < 4; ++vt) {
                short8 vf = *(const short8*)(Vt + (vt * 16 + l16) * 64 + (((quad + c * 4) ^ sw) * 8));
#pragma unroll
                for (int qt = 0; qt < 2; ++qt)
                    acc[vt][qt] = mfma16(vf, pB[qt], acc[vt][qt]);
            }
        }
    }
    // l over this kt-half: reduce over quads (lane bits 4,5)
#pragma unroll
    for (int qt = 0; qt < 2; ++qt) {
        lac[qt] += __shfl_xor(lac[qt], 16, 64);
        lac[qt] += __shfl_xor(lac[qt], 32, 64);
    }
    __syncthreads();  // all tile reads done before Macc aliases Ks
    if (kthalf == 1) {
        float* M = Macc + qhalf * 2048;
#pragma unroll
        for (int qt = 0; qt < 2; ++qt)
#pragma unroll
            for (int vt = 0; vt < 4; ++vt)
                *(f32x4*)(M + (qt * 16 + l16) * 64 + vt * 16 + quad * 4) = acc[vt][qt];
        if (quad == 0) {
            Ml[qhalf * 32 + l16]      = lac[0];
            Ml[qhalf * 32 + 16 + l16] = lac[1];
        }
    }
    __syncthreads();
    if (kthalf == 0) {
        const float* M = Macc + qhalf * 2048;
#pragma unroll
        for (int qt = 0; qt < 2; ++qt) {
            float linv = 1.f / (lac[qt] + Ml[qhalf * 32 + qt * 16 + l16]);
#pragma unroll
            for (int vt = 0; vt < 4; ++vt) {
                f32x4 ap = *(const f32x4*)(M + (qt * 16 + l16) * 64 + vt * 16 + quad * 4);
                s16x4 ov = {tobs((acc[vt][qt][0] + ap[0]) * linv),
                            tobs((acc[vt][qt][1] + ap[1]) * linv),
                            tobs((acc[vt][qt][2] + ap[2]) * linv),
                            tobs((acc[vt][qt][3] + ap[3]) * linv)};
                *(s16x4*)(O + (size_t)(q0 + qt * 16 + l16) * 1024 + h * 64 + vt * 16 + quad * 4) = ov;
            }
        }
    }
}

extern "C" void kernel_launch(void* const* d_in, const int* in_sizes, int n_in,
                              void* d_out, int out_size, void* d_ws, size_t ws_size,
                              hipStream_t stream) {
    const float* x   = (const float*)d_in[0];
    const float* s1  = (const float*)d_in[1];
    const float* b1n = (const float*)d_in[2];
    const float* s2  = (const float*)d_in[3];
    const float* b2n = (const float*)d_in[4];
    const float* Wq  = (const float*)d_in[5];
    const float* bq  = (const float*)d_in[6];
    const float* Wk  = (const float*)d_in[7];
    const float* bk  = (const float*)d_in[8];
    const float* Wv  = (const float*)d_in[9];
    const float* bv  = (const float*)d_in[10];
    const float* Wo  = (const float*)d_in[11];
    const float* bo  = (const float*)d_in[12];
    const float* W1  = (const float*)d_in[13];
    const float* b1  = (const float*)d_in[14];
    const float* W2  = (const float*)d_in[15];
    const float* b2  = (const float*)d_in[16];

    char* ws = (char*)d_ws;
    bf16*  y     = (bf16*)(ws);                    // 8 MiB: ln1 out; later ln2 out; later BT2
    bf16*  QKV   = (bf16*)(ws + (8ull  << 20));    // 24 MiB
    bf16*  o     = (bf16*)(ws + (32ull << 20));    // 8 MiB
    bf16*  hb    = (bf16*)(ws + (40ull << 20));    // 32 MiB (FFN hidden)
    bf16*  BTqkv = (bf16*)(ws + (40ull << 20));    // 6 MiB  (aliases hb; dead before FFN1)
    bf16*  BTo   = (bf16*)(ws + (46ull << 20));    // 2 MiB  (aliases hb; dead before FFN1)
    bf16*  VT    = (bf16*)(ws + (72ull << 20));    // 8 MiB
    bf16*  BT1   = (bf16*)(ws + (82ull << 20));    // 8 MiB
    float* bqkv  = (float*)(ws + (90ull << 20));   // 12 KiB
    bf16*  BT2   = y;                              // written after FFN1 (y dead)
    float* x1    = (float*)d_out;                  // fp32 residual lives in d_out

    // weight transposes (fp32 KxN -> bf16 NxK)
    wtrans<<<dim3(32, 32),  256, 0, stream>>>(Wq, BTqkv,               D, D);
    wtrans<<<dim3(32, 32),  256, 0, stream>>>(Wk, BTqkv + 1024 * 1024, D, D);
    wtrans<<<dim3(32, 32),  256, 0, stream>>>(Wv, BTqkv + 2048 * 1024, D, D);
    wtrans<<<dim3(32, 32),  256, 0, stream>>>(Wo, BTo, D, D);
    wtrans<<<dim3(128, 32), 256, 0, stream>>>(W1, BT1, D, FF);
    bconcat<<<12, 256, 0, stream>>>(bq, bk, bv, bqkv);

    ln_kernel<<<S, 256, 0, stream>>>(x, s1, b1n, y);

    // fused QKV GEMM: (4096 x 3072)
    gemm_bt<EPI_NONE><<<dim3(24, 32), 256, 0, stream>>>(y, BTqkv, bqkv, nullptr, QKV, S, 3072, D);

    rope_kernel<<<(S * H * 32) / 256, 256, 0, stream>>>(QKV);
    vtrans<<<dim3(64, 16), 256, 0, stream>>>((const short*)QKV, (short*)VT);

    attn_kernel<<<H * 64, 256, 0, stream>>>(QKV, VT, o);

    // O projection + residual (fp32) -> x1 (= d_out)
    gemm_bt<EPI_RES><<<dim3(8, 32), 256, 0, stream>>>(o, BTo, bo, x, x1, S, D, D);

    ln_kernel<<<S, 256, 0, stream>>>(x1, s2, b2n, y);

    // FFN1 + GELU
    gemm_bt<EPI_GELU><<<dim3(32, 32), 256, 0, stream>>>(y, BT1, b1, nullptr, hb, S, FF, D);

    // W2 transpose now (y is dead), then FFN2 + residual (in-place on d_out)
    wtrans<<<dim3(32, 128), 256, 0, stream>>>(W2, BT2, FF, D);
    gemm_bt<EPI_RES><<<dim3(8, 32), 256, 0, stream>>>(hb, BT2, b2, x1, d_out, S, D, FF);
}

// Round 6
// 477.841 us; speedup vs baseline: 37.6079x; 1.0362x over previous
//
#include <hip/hip_runtime.h>
#include <hip/hip_bf16.h>
#include <math.h>

using bf16 = __hip_bfloat16;
typedef __attribute__((ext_vector_type(8))) short short8;
typedef __attribute__((ext_vector_type(4))) short s16x4;
typedef __attribute__((ext_vector_type(4))) float f32x4;

constexpr int S = 4096, D = 1024, H = 16, HD = 64, FF = 4096;

static __device__ __forceinline__ float tof(bf16 v) { return __bfloat162float(v); }
static __device__ __forceinline__ bf16 tob(float v) { return __float2bfloat16(v); }
static __device__ __forceinline__ short tobs(float v) {
    bf16 h = __float2bfloat16(v);
    return *reinterpret_cast<short*>(&h);
}
static __device__ __forceinline__ unsigned pkbf16(float a, float b) {
    __hip_bfloat162 h = __float22bfloat162_rn(make_float2(a, b));
    return *reinterpret_cast<unsigned*>(&h);
}

static __device__ __forceinline__ f32x4 mfma16(short8 a, short8 b, f32x4 c) {
    return __builtin_amdgcn_mfma_f32_16x16x32_bf16(a, b, c, 0, 0, 0);
}
// async global->LDS, 16B per lane; LDS dest = wave-uniform base + lane*16
static __device__ __forceinline__ void stage16(const bf16* g, bf16* l) {
    __builtin_amdgcn_global_load_lds((__attribute__((address_space(1))) void*)g,
                                     (__attribute__((address_space(3))) void*)l, 16, 0, 0);
}

// ---------------- LayerNorm: fp32 in -> bf16 out ----------------------------
__global__ __launch_bounds__(256) void ln_kernel(const float* __restrict__ x,
                                                 const float* __restrict__ scale,
                                                 const float* __restrict__ bias,
                                                 bf16* __restrict__ y) {
    int row = blockIdx.x, t = threadIdx.x;
    const float* xr = x + (size_t)row * D;
    float v[4], s = 0.f, ss = 0.f;
#pragma unroll
    for (int i = 0; i < 4; ++i) {
        v[i] = xr[t + 256 * i];
        s += v[i]; ss += v[i] * v[i];
    }
    __shared__ float r0[256], r1[256];
    r0[t] = s; r1[t] = ss;
    __syncthreads();
    for (int off = 128; off; off >>= 1) {
        if (t < off) { r0[t] += r0[t + off]; r1[t] += r1[t + off]; }
        __syncthreads();
    }
    float mu  = r0[0] * (1.f / D);
    float var = r1[0] * (1.f / D) - mu * mu;
    float inv = rsqrtf(var + 1e-6f);
    bf16* yr = y + (size_t)row * D;
#pragma unroll
    for (int i = 0; i < 4; ++i) {
        int c = t + 256 * i;
        yr[c] = tob((v[i] - mu) * inv * scale[c] + bias[c]);
    }
}

// ---------------- Weight transpose+convert: fp32 (K,N) -> bf16 (N,K) --------
__global__ __launch_bounds__(256) void wtrans(const float* __restrict__ W,
                                              bf16* __restrict__ BT, int K, int N) {
    __shared__ float t[32][33];
    int kt = blockIdx.y * 32, nt = blockIdx.x * 32;
    int tid = threadIdx.x, r = tid >> 5, c = tid & 31;
#pragma unroll
    for (int p = 0; p < 4; ++p)
        t[r + p * 8][c] = W[(size_t)(kt + r + p * 8) * N + nt + c];
    __syncthreads();
#pragma unroll
    for (int p = 0; p < 4; ++p)
        BT[(size_t)(nt + r + p * 8) * K + kt + c] = tob(t[c][r + p * 8]);
}

// fused Wq/Wk/Wv transpose via blockIdx.z
__global__ __launch_bounds__(256) void wtrans_qkv(const float* __restrict__ Wq,
                                                  const float* __restrict__ Wk,
                                                  const float* __restrict__ Wv,
                                                  bf16* __restrict__ BT) {
    __shared__ float t[32][33];
    const float* W = blockIdx.z == 0 ? Wq : (blockIdx.z == 1 ? Wk : Wv);
    bf16* dst = BT + (size_t)blockIdx.z * 1024 * 1024;
    int kt = blockIdx.y * 32, nt = blockIdx.x * 32;
    int tid = threadIdx.x, r = tid >> 5, c = tid & 31;
#pragma unroll
    for (int p = 0; p < 4; ++p)
        t[r + p * 8][c] = W[(size_t)(kt + r + p * 8) * 1024 + nt + c];
    __syncthreads();
#pragma unroll
    for (int p = 0; p < 4; ++p)
        dst[(size_t)(nt + r + p * 8) * 1024 + kt + c] = tob(t[c][r + p * 8]);
}

// ---------------- concat qkv biases -----------------------------------------
__global__ void bconcat(const float* __restrict__ bq, const float* __restrict__ bk,
                        const float* __restrict__ bv, float* __restrict__ out) {
    int i = blockIdx.x * 256 + threadIdx.x;  // 3072
    out[i] = i < 1024 ? bq[i] : (i < 2048 ? bk[i - 1024] : bv[i - 2048]);
}

// ---------------- MFMA GEMM: C[M,N] = A[M,K] * BT[N,K]^T + bias -------------
// MT=128: 128x128 tile, 4 waves 2x2 (64x64 each). MT=64: 64x128, wave = 64x32.
#define EPI_NONE 0  // bf16 out
#define EPI_RES  1  // fp32 out = acc + bias + resid(fp32)   (out may alias resid)
#define EPI_GELU 2  // bf16 out = gelu(acc + bias)

template <int EPI, int MT>
__global__ __launch_bounds__(256, MT == 128 ? 2 : 3) void gemm_bt(
    const bf16* __restrict__ A, const bf16* __restrict__ BT,
    const float* __restrict__ bias, const float* resid, void* out,
    int M, int N, int K) {
    constexpr int NJ = (MT == 128) ? 4 : 2;
    __shared__ bf16 As[MT * 32];
    __shared__ bf16 Bs[128 * 32];
    const int tid = threadIdx.x;
    const int w = tid >> 6, lane = tid & 63;
    const int quad = lane >> 4, l16 = lane & 15;
    const int rowBase = blockIdx.y * MT, colBase = blockIdx.x * 128;
    const int wr = (MT == 128) ? (w >> 1) * 64 : 0;
    const int wc = (MT == 128) ? (w & 1) * 64 : w * 32;
    const int sr = lane >> 2, skb = (lane & 3) * 8;
    f32x4 acc[4][NJ] = {};
    for (int k0 = 0; k0 < K; k0 += 32) {
        __syncthreads();
        if (MT == 128) {
#pragma unroll
            for (int t = 0; t < 2; ++t) {
                int inst = w * 2 + t;
                int r = inst * 16 + sr;
                stage16(A  + (size_t)(rowBase + r) * K + k0 + skb, As + inst * 512);
                stage16(BT + (size_t)(colBase + r) * K + k0 + skb, Bs + inst * 512);
            }
        } else {
            stage16(A + (size_t)(rowBase + w * 16 + sr) * K + k0 + skb, As + w * 512);
#pragma unroll
            for (int t = 0; t < 2; ++t) {
                int inst = w + t * 4;
                stage16(BT + (size_t)(colBase + inst * 16 + sr) * K + k0 + skb, Bs + inst * 512);
            }
        }
        __syncthreads();
        const bf16* pa = As + (wr + l16) * 32 + quad * 8;
        const bf16* pb = Bs + (wc + l16) * 32 + quad * 8;
        short8 a[4], b[NJ];
#pragma unroll
        for (int i = 0; i < 4; ++i) a[i] = *(const short8*)(pa + i * 512);
#pragma unroll
        for (int j = 0; j < NJ; ++j) b[j] = *(const short8*)(pb + j * 512);
#pragma unroll
        for (int i = 0; i < 4; ++i)
#pragma unroll
            for (int j = 0; j < NJ; ++j) acc[i][j] = mfma16(a[i], b[j], acc[i][j]);
    }
#pragma unroll
    for (int j = 0; j < NJ; ++j) {
        int c = colBase + wc + j * 16 + l16;
        float bj = bias[c];
#pragma unroll
        for (int i = 0; i < 4; ++i) {
            int r0 = rowBase + wr + i * 16 + quad * 4;
#pragma unroll
            for (int reg = 0; reg < 4; ++reg) {
                size_t idx = (size_t)(r0 + reg) * N + c;
                float val = acc[i][j][reg] + bj;
                if (EPI == EPI_NONE) {
                    ((bf16*)out)[idx] = tob(val);
                } else if (EPI == EPI_RES) {
                    ((float*)out)[idx] = val + resid[idx];
                } else {
                    float g = 0.5f * val * (1.f + erff(val * 0.70710678118f));
                    ((bf16*)out)[idx] = tob(g);
                }
            }
        }
    }
}

// ---------------- RoPE on fused QKV -----------------------------------------
// q scaled by (1/sqrt(HD)) * log2(e) so attention can use exp2 directly.
__global__ __launch_bounds__(256) void rope_kernel(bf16* __restrict__ QKV) {
    int idx = blockIdx.x * 256 + threadIdx.x;  // S*H*32 pair slots
    int s = idx >> 9, rem = idx & 511, h = rem >> 5, c = rem & 31;
    float freq = __expf(-(float)c * (9.210340371976184f / 32.f));
    float ang = (float)s * freq, sn, cs;
    sincosf(ang, &sn, &cs);
    const float qs = 0.125f * 1.44269504088896f;
    size_t base = (size_t)s * 3072 + h * 64 + c;
    float q1 = tof(QKV[base]), q2 = tof(QKV[base + 32]);
    QKV[base]      = tob((q1 * cs - q2 * sn) * qs);
    QKV[base + 32] = tob((q2 * cs + q1 * sn) * qs);
    float k1 = tof(QKV[base + 1024]), k2 = tof(QKV[base + 1056]);
    QKV[base + 1024] = tob(k1 * cs - k2 * sn);
    QKV[base + 1056] = tob(k2 * cs + k1 * sn);
}

// ---------------- V transpose: QKV v-part -> VT[h][c][s], 64 rows/head ------
__global__ __launch_bounds__(256) void vtrans(const short* __restrict__ QKV,
                                              short* __restrict__ VT) {
    int h = blockIdx.y, st = blockIdx.x * 64;
    __shared__ short t[64][72];
    int tid = threadIdx.x, r0 = tid >> 3, c0 = (tid & 7) * 8;
#pragma unroll
    for (int p = 0; p < 2; ++p) {
        int r = r0 + p * 32;
        short8 d = *(const short8*)(QKV + (size_t)(st + r) * 3072 + 2048 + h * 64 + c0);
#pragma unroll
        for (int j = 0; j < 8; ++j) t[r][c0 + j] = d[j];
    }
    __syncthreads();
#pragma unroll
    for (int p = 0; p < 2; ++p) {
        int c = r0 + p * 32;
        short8 v;
#pragma unroll
        for (int j = 0; j < 8; ++j) v[j] = t[c0 + j][c];
        *(short8*)(VT + ((size_t)h * 64 + c) * 4096 + st + c0) = v;
    }
}

// ---------------- Flash attention v4: wave = 16 q-rows, full kt range -------
// block = 4 waves over 64 q-rows of one head; 64-key tiles staged to LDS and
// shared by all 4 waves; l via MFMA ones-fragment; no cross-wave merge.
__global__ __launch_bounds__(256, 4) void attn_kernel(const bf16* __restrict__ QKV,
                                                      const bf16* __restrict__ VT,
                                                      bf16* __restrict__ O) {
    const int h = blockIdx.x >> 6, qb = blockIdx.x & 63;
    const int w = threadIdx.x >> 6, lane = threadIdx.x & 63;
    const int quad = lane >> 4, l16 = lane & 15;
    const int q0w = qb * 64 + w * 16;
    const bf16* Qh = QKV + h * 64;
    const bf16* Kh = QKV + 1024 + h * 64;
    const bf16* Vh = VT + (size_t)h * 64 * 4096;

    // LDS 24 KiB: Ks 8K | Vs 8K | P 4x2K (wave-private)
    __shared__ char smem[24576];
    bf16* Ks = (bf16*)(smem);
    bf16* Vs = (bf16*)(smem + 8192);
    char* Pb = smem + 16384 + w * 2048;

    const int sw = l16 & 7;                       // frag XOR swizzle key (row&7)
    const int rloc = lane >> 3, slot = lane & 7;  // staging: 8 rows x 8 chunks
    const int schunk = (slot ^ rloc) * 8;

    // Q frags (loop-invariant): B-operand n=l16 (q), k=quad*8+j (hd)
    short8 qf[2];
#pragma unroll
    for (int c = 0; c < 2; ++c)
        qf[c] = *(const short8*)(Qh + (size_t)(q0w + l16) * 3072 + c * 32 + quad * 8);

    // ones A-fragment: row m=0 all-ones -> acc_l row 0 = sum_k P[k][q] = l
    const short ob = (l16 == 0) ? (short)0x3F80 : (short)0;
    const short8 ones8 = {ob, ob, ob, ob, ob, ob, ob, ob};

    f32x4 acc[4] = {};
    f32x4 accl = {};
    const f32x4 zero = {0.f, 0.f, 0.f, 0.f};

    for (int kt = 0; kt < 4096; kt += 64) {
        __syncthreads();  // previous iter's tile reads complete
        {
            int r = (2 * w /*+t*/) * 8 + rloc;  // t=0
            stage16(Kh + (size_t)(kt + r) * 3072 + schunk, Ks + 2 * w * 512);
            stage16(Vh + (size_t)r * 4096 + kt + schunk, Vs + 2 * w * 512);
            int r1 = (2 * w + 1) * 8 + rloc;
            stage16(Kh + (size_t)(kt + r1) * 3072 + schunk, Ks + (2 * w + 1) * 512);
            stage16(Vh + (size_t)r1 * 4096 + kt + schunk, Vs + (2 * w + 1) * 512);
        }
        __syncthreads();  // DMA drained (vmcnt(0) before barrier)

        // S^T: A = K rows (m=key), B = Q (n=q)
        f32x4 st[4];
#pragma unroll
        for (int nt = 0; nt < 4; ++nt) {
            const bf16* kr = Ks + (nt * 16 + l16) * 64;
            short8 k0 = *(const short8*)(kr + ((quad ^ sw) * 8));
            short8 k1 = *(const short8*)(kr + (((quad + 4) ^ sw) * 8));
            st[nt] = mfma16(k1, qf[1], mfma16(k0, qf[0], zero));
        }
        // P^T = exp2(S^T): lane holds keys nt*16+quad*4+{0..3} of q=l16
#pragma unroll
        for (int nt = 0; nt < 4; ++nt) {
            float e0 = exp2f(st[nt][0]), e1 = exp2f(st[nt][1]);
            float e2 = exp2f(st[nt][2]), e3 = exp2f(st[nt][3]);
            uint2 pk = {pkbf16(e0, e1), pkbf16(e2, e3)};
            *(uint2*)(Pb + l16 * 128 + (((nt * 2 + (quad >> 1)) ^ sw) * 16) + (quad & 1) * 8) = pk;
        }
        asm volatile("s_waitcnt lgkmcnt(0)" ::: "memory");
        // PV: A = V^T (m=vdim), B = P^T (n=q, k=key); ones-row -> l
#pragma unroll
        for (int c = 0; c < 2; ++c) {
            short8 pB = *(const short8*)(Pb + l16 * 128 + (((c * 4 + quad) ^ sw) * 16));
            accl = mfma16(ones8, pB, accl);
#pragma unroll
            for (int vt = 0; vt < 4; ++vt) {
                short8 vf = *(const short8*)(Vs + (vt * 16 + l16) * 64 + (((c * 4 + quad) ^ sw) * 8));
                acc[vt] = mfma16(vf, pB, acc[vt]);
            }
        }
    }
    // l[q] sits in accl reg 0 at lane q (quad 0); broadcast to all quads
    float linv = 1.f / __shfl(accl[0], l16, 64);
#pragma unroll
    for (int vt = 0; vt < 4; ++vt) {
        s16x4 ov = {tobs(acc[vt][0] * linv), tobs(acc[vt][1] * linv),
                    tobs(acc[vt][2] * linv), tobs(acc[vt][3] * linv)};
        *(s16x4*)(O + (size_t)(q0w + l16) * 1024 + h * 64 + vt * 16 + quad * 4) = ov;
    }
}

extern "C" void kernel_launch(void* const* d_in, const int* in_sizes, int n_in,
                              void* d_out, int out_size, void* d_ws, size_t ws_size,
                              hipStream_t stream) {
    const float* x   = (const float*)d_in[0];
    const float* s1  = (const float*)d_in[1];
    const float* b1n = (const float*)d_in[2];
    const float* s2  = (const float*)d_in[3];
    const float* b2n = (const float*)d_in[4];
    const float* Wq  = (const float*)d_in[5];
    const float* bq  = (const float*)d_in[6];
    const float* Wk  = (const float*)d_in[7];
    const float* bk  = (const float*)d_in[8];
    const float* Wv  = (const float*)d_in[9];
    const float* bv  = (const float*)d_in[10];
    const float* Wo  = (const float*)d_in[11];
    const float* bo  = (const float*)d_in[12];
    const float* W1  = (const float*)d_in[13];
    const float* b1  = (const float*)d_in[14];
    const float* W2  = (const float*)d_in[15];
    const float* b2  = (const float*)d_in[16];

    char* ws = (char*)d_ws;
    bf16*  y     = (bf16*)(ws);                    // 8 MiB: ln1 out; later ln2 out; later BT2
    bf16*  QKV   = (bf16*)(ws + (8ull  << 20));    // 24 MiB
    bf16*  o     = (bf16*)(ws + (32ull << 20));    // 8 MiB
    bf16*  hb    = (bf16*)(ws + (40ull << 20));    // 32 MiB (FFN hidden)
    bf16*  BTqkv = (bf16*)(ws + (40ull << 20));    // 6 MiB  (aliases hb; dead before FFN1)
    bf16*  BTo   = (bf16*)(ws + (46ull << 20));    // 2 MiB  (aliases hb; dead before FFN1)
    bf16*  VT    = (bf16*)(ws + (72ull << 20));    // 8 MiB
    bf16*  BT1   = (bf16*)(ws + (82ull << 20));    // 8 MiB
    float* bqkv  = (float*)(ws + (90ull << 20));   // 12 KiB
    bf16*  BT2   = y;                              // written after FFN1 (y dead)
    float* x1    = (float*)d_out;                  // fp32 residual lives in d_out

    // weight transposes (fp32 KxN -> bf16 NxK)
    wtrans_qkv<<<dim3(32, 32, 3), 256, 0, stream>>>(Wq, Wk, Wv, BTqkv);
    wtrans<<<dim3(32, 32),  256, 0, stream>>>(Wo, BTo, D, D);
    wtrans<<<dim3(128, 32), 256, 0, stream>>>(W1, BT1, D, FF);
    bconcat<<<12, 256, 0, stream>>>(bq, bk, bv, bqkv);

    ln_kernel<<<S, 256, 0, stream>>>(x, s1, b1n, y);

    // fused QKV GEMM: (4096 x 3072)
    gemm_bt<EPI_NONE, 128><<<dim3(24, 32), 256, 0, stream>>>(y, BTqkv, bqkv, nullptr, QKV, S, 3072, D);

    rope_kernel<<<(S * H * 32) / 256, 256, 0, stream>>>(QKV);
    vtrans<<<dim3(64, 16), 256, 0, stream>>>((const short*)QKV, (short*)VT);

    attn_kernel<<<H * 64, 256, 0, stream>>>(QKV, VT, o);

    // O projection + residual (fp32) -> x1 (= d_out)
    gemm_bt<EPI_RES, 64><<<dim3(8, 64), 256, 0, stream>>>(o, BTo, bo, x, x1, S, D, D);

    ln_kernel<<<S, 256, 0, stream>>>(x1, s2, b2n, y);

    // FFN1 + GELU
    gemm_bt<EPI_GELU, 128><<<dim3(32, 32), 256, 0, stream>>>(y, BT1, b1, nullptr, hb, S, FF, D);

    // W2 transpose now (y is dead), then FFN2 + residual (in-place on d_out)
    wtrans<<<dim3(32, 128), 256, 0, stream>>>(W2, BT2, FF, D);
    gemm_bt<EPI_RES, 64><<<dim3(8, 64), 256, 0, stream>>>(hb, BT2, b2, x1, d_out, S, D, FF);
}

// Round 7
// 433.194 us; speedup vs baseline: 41.4839x; 1.1031x over previous
//
#include <hip/hip_runtime.h>
#include <hip/hip_bf16.h>
#include <math.h>

using bf16 = __hip_bfloat16;
typedef __attribute__((ext_vector_type(8))) short short8;
typedef __attribute__((ext_vector_type(4))) short s16x4;
typedef __attribute__((ext_vector_type(4))) float f32x4;

constexpr int S = 4096, D = 1024, H = 16, HD = 64, FF = 4096;

static __device__ __forceinline__ float tof(bf16 v) { return __bfloat162float(v); }
static __device__ __forceinline__ bf16 tob(float v) { return __float2bfloat16(v); }
static __device__ __forceinline__ short tobs(float v) {
    bf16 h = __float2bfloat16(v);
    return *reinterpret_cast<short*>(&h);
}
static __device__ __forceinline__ unsigned pkbf16(float a, float b) {
    __hip_bfloat162 h = __float22bfloat162_rn(make_float2(a, b));
    return *reinterpret_cast<unsigned*>(&h);
}

#if __has_builtin(__builtin_amdgcn_exp2f)
#define EXP2(x) __builtin_amdgcn_exp2f(x)
#else
#define EXP2(x) exp2f(x)
#endif

static __device__ __forceinline__ f32x4 mfma16(short8 a, short8 b, f32x4 c) {
    return __builtin_amdgcn_mfma_f32_16x16x32_bf16(a, b, c, 0, 0, 0);
}
// async global->LDS, 16B per lane; LDS dest = wave-uniform base + lane*16
static __device__ __forceinline__ void stage16(const bf16* g, bf16* l) {
    __builtin_amdgcn_global_load_lds((__attribute__((address_space(1))) void*)g,
                                     (__attribute__((address_space(3))) void*)l, 16, 0, 0);
}

// ---------------- LayerNorm: fp32 in -> bf16 out ----------------------------
__global__ __launch_bounds__(256) void ln_kernel(const float* __restrict__ x,
                                                 const float* __restrict__ scale,
                                                 const float* __restrict__ bias,
                                                 bf16* __restrict__ y) {
    int row = blockIdx.x, t = threadIdx.x;
    const float* xr = x + (size_t)row * D;
    float v[4], s = 0.f, ss = 0.f;
#pragma unroll
    for (int i = 0; i < 4; ++i) {
        v[i] = xr[t + 256 * i];
        s += v[i]; ss += v[i] * v[i];
    }
    __shared__ float r0[256], r1[256];
    r0[t] = s; r1[t] = ss;
    __syncthreads();
    for (int off = 128; off; off >>= 1) {
        if (t < off) { r0[t] += r0[t + off]; r1[t] += r1[t + off]; }
        __syncthreads();
    }
    float mu  = r0[0] * (1.f / D);
    float var = r1[0] * (1.f / D) - mu * mu;
    float inv = rsqrtf(var + 1e-6f);
    bf16* yr = y + (size_t)row * D;
#pragma unroll
    for (int i = 0; i < 4; ++i) {
        int c = t + 256 * i;
        yr[c] = tob((v[i] - mu) * inv * scale[c] + bias[c]);
    }
}

// ------- all weight transposes (fp32 KxN -> bf16 NxK) + bias concat, fused --
// blocks 0..3071: Wq/Wk/Wv | 3072..4095: Wo | 4096..8191: W1 | 8192..12287: W2
// blocks 12288..12299: qkv bias concat
__global__ __launch_bounds__(256) void wtrans_all(
    const float* __restrict__ Wq, const float* __restrict__ Wk,
    const float* __restrict__ Wv, const float* __restrict__ Wo,
    const float* __restrict__ W1, const float* __restrict__ W2,
    const float* __restrict__ bq, const float* __restrict__ bk,
    const float* __restrict__ bv,
    bf16* __restrict__ BTqkv, bf16* __restrict__ BTo,
    bf16* __restrict__ BT1, bf16* __restrict__ BT2, float* __restrict__ bqkv) {
    int id = blockIdx.x;
    if (id >= 12288) {
        int i = (id - 12288) * 256 + threadIdx.x;  // 3072
        bqkv[i] = i < 1024 ? bq[i] : (i < 2048 ? bk[i - 1024] : bv[i - 2048]);
        return;
    }
    const float* W; bf16* dst; int K, N, local;
    if (id < 3072)      { int s = id >> 10; W = s == 0 ? Wq : (s == 1 ? Wk : Wv);
                          dst = BTqkv + (size_t)s * 1048576; K = 1024; N = 1024; local = id & 1023; }
    else if (id < 4096) { W = Wo; dst = BTo; K = 1024; N = 1024; local = id - 3072; }
    else if (id < 8192) { W = W1; dst = BT1; K = 1024; N = 4096; local = id - 4096; }
    else                { W = W2; dst = BT2; K = 4096; N = 1024; local = id - 8192; }
    int ls = (N == 4096) ? 7 : 5;                  // log2(N/32)
    int nt = (local & ((1 << ls) - 1)) << 5, kt = (local >> ls) << 5;
    __shared__ float t[32][33];
    int tid = threadIdx.x, r = tid >> 5, c = tid & 31;
#pragma unroll
    for (int p = 0; p < 4; ++p)
        t[r + p * 8][c] = W[(size_t)(kt + r + p * 8) * N + nt + c];
    __syncthreads();
#pragma unroll
    for (int p = 0; p < 4; ++p)
        dst[(size_t)(nt + r + p * 8) * K + kt + c] = tob(t[c][r + p * 8]);
}

// ---------------- MFMA GEMM: C[M,N] = A[M,K] * BT[N,K]^T + bias -------------
// MT=128: 128x128 tile, 4 waves 2x2 (64x64 each). MT=64: 64x128, wave = 64x32.
#define EPI_RES  1  // fp32 out = acc + bias + resid(fp32)   (out may alias resid)
#define EPI_GELU 2  // bf16 out = gelu(acc + bias)
#define EPI_QKV  3  // q/k: +bias, rope, (q: *1/8*log2e) -> QKV; v: -> VT transposed

template <int EPI, int MT>
__global__ __launch_bounds__(256, MT == 128 ? 2 : 3) void gemm_bt(
    const bf16* __restrict__ A, const bf16* __restrict__ BT,
    const float* __restrict__ bias, const float* resid, void* out, void* out2,
    int M, int N, int K) {
    constexpr int NJ = (MT == 128) ? 4 : 2;
    __shared__ bf16 As[MT * 32];
    __shared__ bf16 Bs[128 * 32];
    const int tid = threadIdx.x;
    const int w = tid >> 6, lane = tid & 63;
    const int quad = lane >> 4, l16 = lane & 15;
    const int rowBase = blockIdx.y * MT, colBase = blockIdx.x * 128;
    const int wr = (MT == 128) ? (w >> 1) * 64 : 0;
    const int wc = (MT == 128) ? (w & 1) * 64 : w * 32;
    const int sr = lane >> 2, skb = (lane & 3) * 8;
    f32x4 acc[4][NJ] = {};
    for (int k0 = 0; k0 < K; k0 += 32) {
        __syncthreads();
        if (MT == 128) {
#pragma unroll
            for (int t = 0; t < 2; ++t) {
                int inst = w * 2 + t;
                int r = inst * 16 + sr;
                stage16(A  + (size_t)(rowBase + r) * K + k0 + skb, As + inst * 512);
                stage16(BT + (size_t)(colBase + r) * K + k0 + skb, Bs + inst * 512);
            }
        } else {
            stage16(A + (size_t)(rowBase + w * 16 + sr) * K + k0 + skb, As + w * 512);
#pragma unroll
            for (int t = 0; t < 2; ++t) {
                int inst = w + t * 4;
                stage16(BT + (size_t)(colBase + inst * 16 + sr) * K + k0 + skb, Bs + inst * 512);
            }
        }
        __syncthreads();
        const bf16* pa = As + (wr + l16) * 32 + quad * 8;
        const bf16* pb = Bs + (wc + l16) * 32 + quad * 8;
        short8 a[4], b[NJ];
#pragma unroll
        for (int i = 0; i < 4; ++i) a[i] = *(const short8*)(pa + i * 512);
#pragma unroll
        for (int j = 0; j < NJ; ++j) b[j] = *(const short8*)(pb + j * 512);
#pragma unroll
        for (int i = 0; i < 4; ++i)
#pragma unroll
            for (int j = 0; j < NJ; ++j) acc[i][j] = mfma16(a[i], b[j], acc[i][j]);
    }
    if (EPI == EPI_QKV) {
        bf16* QKVo = (bf16*)out;
        bf16* VTo  = (bf16*)out2;
        if (colBase >= 2048) {  // V section: write transposed VT[c-2048][s]
#pragma unroll
            for (int j = 0; j < NJ; ++j) {
                int c = colBase + wc + j * 16 + l16;
                float bj = bias[c];
                size_t cc = (size_t)(c - 2048) * 4096;
#pragma unroll
                for (int i = 0; i < 4; ++i) {
                    int r0 = rowBase + wr + i * 16 + quad * 4;
                    s16x4 ov = {tobs(acc[i][j][0] + bj), tobs(acc[i][j][1] + bj),
                                tobs(acc[i][j][2] + bj), tobs(acc[i][j][3] + bj)};
                    *(s16x4*)(VTo + cc + r0) = ov;
                }
            }
        } else {  // Q or K section: bias + rope (pairs are (j, j+2) in-lane)
            const bool isq = colBase < 1024;
            const float qs = isq ? 0.125f * 1.44269504088896f : 1.f;
#pragma unroll
            for (int j2 = 0; j2 < 2; ++j2) {
                int dim = j2 * 16 + l16;  // 0..31 ((wc+j*16+l16)&63, wc&63==0)
                float freq = __expf(-(float)dim * (9.210340371976184f / 32.f));
                int c1 = colBase + wc + j2 * 16 + l16, c2 = c1 + 32;
                float b1v = bias[c1], b2v = bias[c2];
#pragma unroll
                for (int i = 0; i < 4; ++i) {
#pragma unroll
                    for (int reg = 0; reg < 4; ++reg) {
                        int s = rowBase + wr + i * 16 + quad * 4 + reg;
                        float sn, cs;
                        sincosf((float)s * freq, &sn, &cs);
                        float x1 = acc[i][j2][reg] + b1v;
                        float x2 = acc[i][j2 + 2][reg] + b2v;
                        QKVo[(size_t)s * 3072 + c1] = tob((x1 * cs - x2 * sn) * qs);
                        QKVo[(size_t)s * 3072 + c2] = tob((x2 * cs + x1 * sn) * qs);
                    }
                }
            }
        }
    } else {
#pragma unroll
        for (int j = 0; j < NJ; ++j) {
            int c = colBase + wc + j * 16 + l16;
            float bj = bias[c];
#pragma unroll
            for (int i = 0; i < 4; ++i) {
                int r0 = rowBase + wr + i * 16 + quad * 4;
#pragma unroll
                for (int reg = 0; reg < 4; ++reg) {
                    size_t idx = (size_t)(r0 + reg) * N + c;
                    float val = acc[i][j][reg] + bj;
                    if (EPI == EPI_RES) {
                        ((float*)out)[idx] = val + resid[idx];
                    } else {
                        float g = 0.5f * val * (1.f + erff(val * 0.70710678118f));
                        ((bf16*)out)[idx] = tob(g);
                    }
                }
            }
        }
    }
}

// ---------------- Flash attention v5: single-barrier double-buffered --------
// block = 4 waves over 64 q-rows of one head; 64-key K/V tiles double-buffered
// in LDS; stage(i+1) issued after the barrier opening compute(i) so the DMA
// overlaps a full compute phase. l via MFMA ones-fragment.
__global__ __launch_bounds__(256, 4) void attn_kernel(const bf16* __restrict__ QKV,
                                                      const bf16* __restrict__ VT,
                                                      bf16* __restrict__ O) {
    const int h = blockIdx.x >> 6, qb = blockIdx.x & 63;
    const int w = threadIdx.x >> 6, lane = threadIdx.x & 63;
    const int quad = lane >> 4, l16 = lane & 15;
    const int q0w = qb * 64 + w * 16;
    const bf16* Qh = QKV + h * 64;
    const bf16* Kh = QKV + 1024 + h * 64;
    const bf16* Vh = VT + (size_t)h * 64 * 4096;

    // LDS 40 KiB: Ks[2][4K] | Vs[2][4K] | P 4x2K  -> exactly 4 blocks/CU
    __shared__ char smem[40960];
    bf16* Ks = (bf16*)(smem);
    bf16* Vs = (bf16*)(smem + 16384);
    char* Pb = smem + 32768 + w * 2048;

    const int sw = l16 & 7;                       // frag XOR swizzle key
    const int rloc = lane >> 3, slot = lane & 7;  // staging: 8 rows x 8 chunks
    const int schunk = (slot ^ rloc) * 8;
    const int row0 = 2 * w * 8 + rloc, row1 = (2 * w + 1) * 8 + rloc;
    const size_t kOff0 = (size_t)row0 * 3072 + schunk;
    const size_t kOff1 = (size_t)row1 * 3072 + schunk;
    const size_t vOff0 = (size_t)row0 * 4096 + schunk;
    const size_t vOff1 = (size_t)row1 * 4096 + schunk;

    // Q frags (loop-invariant): B-operand n=l16 (q), k=quad*8+j (hd)
    short8 qf[2];
#pragma unroll
    for (int c = 0; c < 2; ++c)
        qf[c] = *(const short8*)(Qh + (size_t)(q0w + l16) * 3072 + c * 32 + quad * 8);

    // ones A-fragment: row m=0 all-ones -> accl row 0 = sum_k P[k][q] = l
    const short ob = (l16 == 0) ? (short)0x3F80 : (short)0;
    const short8 ones8 = {ob, ob, ob, ob, ob, ob, ob, ob};

    f32x4 acc[4] = {};
    f32x4 accl = {};
    const f32x4 zero = {0.f, 0.f, 0.f, 0.f};

    auto stage = [&](int sel, int kt) {
        bf16* kd = Ks + sel * 4096 + 2 * w * 512;
        bf16* vd = Vs + sel * 4096 + 2 * w * 512;
        const bf16* kb = Kh + (size_t)kt * 3072;
        stage16(kb + kOff0, kd);
        stage16(kb + kOff1, kd + 512);
        stage16(Vh + vOff0 + kt, vd);
        stage16(Vh + vOff1 + kt, vd + 512);
    };
    auto compute = [&](int sel) {
        const bf16* Kt = Ks + sel * 4096;
        const bf16* Vt = Vs + sel * 4096;
        f32x4 st[4];
#pragma unroll
        for (int nt = 0; nt < 4; ++nt) {
            const bf16* kr = Kt + (nt * 16 + l16) * 64;
            short8 k0 = *(const short8*)(kr + ((quad ^ sw) * 8));
            short8 k1 = *(const short8*)(kr + (((quad + 4) ^ sw) * 8));
            st[nt] = mfma16(k1, qf[1], mfma16(k0, qf[0], zero));
        }
#pragma unroll
        for (int nt = 0; nt < 4; ++nt) {
            float e0 = EXP2(st[nt][0]), e1 = EXP2(st[nt][1]);
            float e2 = EXP2(st[nt][2]), e3 = EXP2(st[nt][3]);
            uint2 pk = {pkbf16(e0, e1), pkbf16(e2, e3)};
            *(uint2*)(Pb + l16 * 128 + (((nt * 2 + (quad >> 1)) ^ sw) * 16) + (quad & 1) * 8) = pk;
        }
        asm volatile("s_waitcnt lgkmcnt(0)" ::: "memory");
#pragma unroll
        for (int c = 0; c < 2; ++c) {
            short8 pB = *(const short8*)(Pb + l16 * 128 + (((c * 4 + quad) ^ sw) * 16));
            accl = mfma16(ones8, pB, accl);
#pragma unroll
            for (int vt = 0; vt < 4; ++vt) {
                short8 vf = *(const short8*)(Vt + (vt * 16 + l16) * 64 + (((c * 4 + quad) ^ sw) * 8));
                acc[vt] = mfma16(vf, pB, acc[vt]);
            }
        }
    };

    stage(0, 0);
    for (int kt = 0; kt < 4096; kt += 128) {
        __syncthreads();            // drains DMA(buf0); all readers of buf1 done
        stage(1, kt + 64);          // kt+64 <= 4032 always valid
        compute(0);
        __syncthreads();            // drains DMA(buf1); all readers of buf0 done
        if (kt + 128 < 4096) stage(0, kt + 128);
        compute(1);
    }

    // l[q] sits in accl reg 0 at lane q (quad 0); broadcast to all quads
    float linv = 1.f / __shfl(accl[0], l16, 64);
#pragma unroll
    for (int vt = 0; vt < 4; ++vt) {
        s16x4 ov = {tobs(acc[vt][0] * linv), tobs(acc[vt][1] * linv),
                    tobs(acc[vt][2] * linv), tobs(acc[vt][3] * linv)};
        *(s16x4*)(O + (size_t)(q0w + l16) * 1024 + h * 64 + vt * 16 + quad * 4) = ov;
    }
}

extern "C" void kernel_launch(void* const* d_in, const int* in_sizes, int n_in,
                              void* d_out, int out_size, void* d_ws, size_t ws_size,
                              hipStream_t stream) {
    const float* x   = (const float*)d_in[0];
    const float* s1  = (const float*)d_in[1];
    const float* b1n = (const float*)d_in[2];
    const float* s2  = (const float*)d_in[3];
    const float* b2n = (const float*)d_in[4];
    const float* Wq  = (const float*)d_in[5];
    const float* bq  = (const float*)d_in[6];
    const float* Wk  = (const float*)d_in[7];
    const float* bk  = (const float*)d_in[8];
    const float* Wv  = (const float*)d_in[9];
    const float* bv  = (const float*)d_in[10];
    const float* Wo  = (const float*)d_in[11];
    const float* bo  = (const float*)d_in[12];
    const float* W1  = (const float*)d_in[13];
    const float* b1  = (const float*)d_in[14];
    const float* W2  = (const float*)d_in[15];
    const float* b2  = (const float*)d_in[16];

    char* ws = (char*)d_ws;                        // 96 MiB total
    bf16*  y     = (bf16*)(ws);                    // 0-8 MiB: ln1/ln2 out
    bf16*  QKV   = (bf16*)(ws + (8ull  << 20));    // 8-32 MiB (q,k roped; v unused cols)
    bf16*  o     = (bf16*)(ws + (32ull << 20));    // 32-40 MiB (attn out; bqkv dead by then)
    bf16*  hb    = (bf16*)(ws + (40ull << 20));    // 40-72 MiB (FFN hidden)
    bf16*  BTqkv = (bf16*)(ws + (40ull << 20));    // 40-46 (aliases hb; dead before FFN1)
    bf16*  BTo   = (bf16*)(ws + (46ull << 20));    // 46-48 (aliases hb; dead before FFN1)
    bf16*  VT    = (bf16*)(ws + (72ull << 20));    // 72-80 MiB
    bf16*  BT1   = (bf16*)(ws + (80ull << 20));    // 80-88 MiB
    bf16*  BT2   = (bf16*)(ws + (88ull << 20));    // 88-96 MiB
    float* bqkv  = (float*)(ws + (32ull << 20));   // 12 KiB inside o (read before attn)
    float* x1    = (float*)d_out;                  // fp32 residual lives in d_out

    // all weight transposes + bias concat, one launch
    wtrans_all<<<12300, 256, 0, stream>>>(Wq, Wk, Wv, Wo, W1, W2, bq, bk, bv,
                                          BTqkv, BTo, BT1, BT2, bqkv);

    ln_kernel<<<S, 256, 0, stream>>>(x, s1, b1n, y);

    // fused QKV GEMM (4096x3072) with rope+scale epilogue; V written to VT
    gemm_bt<EPI_QKV, 128><<<dim3(24, 32), 256, 0, stream>>>(y, BTqkv, bqkv, nullptr, QKV, VT, S, 3072, D);

    attn_kernel<<<H * 64, 256, 0, stream>>>(QKV, VT, o);

    // O projection + residual (fp32) -> x1 (= d_out)
    gemm_bt<EPI_RES, 64><<<dim3(8, 64), 256, 0, stream>>>(o, BTo, bo, x, x1, nullptr, S, D, D);

    ln_kernel<<<S, 256, 0, stream>>>(x1, s2, b2n, y);

    // FFN1 + GELU
    gemm_bt<EPI_GELU, 128><<<dim3(32, 32), 256, 0, stream>>>(y, BT1, b1, nullptr, hb, nullptr, S, FF, D);

    // FFN2 + residual (in-place on d_out)
    gemm_bt<EPI_RES, 64><<<dim3(8, 64), 256, 0, stream>>>(hb, BT2, b2, x1, d_out, nullptr, S, D, FF);
}

// Round 8
// 422.870 us; speedup vs baseline: 42.4967x; 1.0244x over previous
//
#include <hip/hip_runtime.h>
#include <hip/hip_bf16.h>
#include <math.h>

using bf16 = __hip_bfloat16;
typedef __attribute__((ext_vector_type(8))) short short8;
typedef __attribute__((ext_vector_type(4))) short s16x4;
typedef __attribute__((ext_vector_type(4))) float f32x4;

constexpr int S = 4096, D = 1024, H = 16, HD = 64, FF = 4096;

static __device__ __forceinline__ float tof(bf16 v) { return __bfloat162float(v); }
static __device__ __forceinline__ bf16 tob(float v) { return __float2bfloat16(v); }
static __device__ __forceinline__ short tobs(float v) {
    bf16 h = __float2bfloat16(v);
    return *reinterpret_cast<short*>(&h);
}
static __device__ __forceinline__ unsigned pkbf16(float a, float b) {
    __hip_bfloat162 h = __float22bfloat162_rn(make_float2(a, b));
    return *reinterpret_cast<unsigned*>(&h);
}

#if __has_builtin(__builtin_amdgcn_exp2f)
#define EXP2(x) __builtin_amdgcn_exp2f(x)
#else
#define EXP2(x) exp2f(x)
#endif

static __device__ __forceinline__ f32x4 mfma16(short8 a, short8 b, f32x4 c) {
    return __builtin_amdgcn_mfma_f32_16x16x32_bf16(a, b, c, 0, 0, 0);
}
// async global->LDS, 16B per lane; LDS dest = wave-uniform base + lane*16
static __device__ __forceinline__ void stage16(const bf16* g, bf16* l) {
    __builtin_amdgcn_global_load_lds((__attribute__((address_space(1))) void*)g,
                                     (__attribute__((address_space(3))) void*)l, 16, 0, 0);
}

// ---------------- LayerNorm: fp32 in -> bf16 out ----------------------------
__global__ __launch_bounds__(256) void ln_kernel(const float* __restrict__ x,
                                                 const float* __restrict__ scale,
                                                 const float* __restrict__ bias,
                                                 bf16* __restrict__ y) {
    int row = blockIdx.x, t = threadIdx.x;
    const float* xr = x + (size_t)row * D;
    float v[4], s = 0.f, ss = 0.f;
#pragma unroll
    for (int i = 0; i < 4; ++i) {
        v[i] = xr[t + 256 * i];
        s += v[i]; ss += v[i] * v[i];
    }
    __shared__ float r0[256], r1[256];
    r0[t] = s; r1[t] = ss;
    __syncthreads();
    for (int off = 128; off; off >>= 1) {
        if (t < off) { r0[t] += r0[t + off]; r1[t] += r1[t + off]; }
        __syncthreads();
    }
    float mu  = r0[0] * (1.f / D);
    float var = r1[0] * (1.f / D) - mu * mu;
    float inv = rsqrtf(var + 1e-6f);
    bf16* yr = y + (size_t)row * D;
#pragma unroll
    for (int i = 0; i < 4; ++i) {
        int c = t + 256 * i;
        yr[c] = tob((v[i] - mu) * inv * scale[c] + bias[c]);
    }
}

// ------- all weight transposes (fp32 KxN -> bf16 NxK) + bias concat, fused --
__global__ __launch_bounds__(256) void wtrans_all(
    const float* __restrict__ Wq, const float* __restrict__ Wk,
    const float* __restrict__ Wv, const float* __restrict__ Wo,
    const float* __restrict__ W1, const float* __restrict__ W2,
    const float* __restrict__ bq, const float* __restrict__ bk,
    const float* __restrict__ bv,
    bf16* __restrict__ BTqkv, bf16* __restrict__ BTo,
    bf16* __restrict__ BT1, bf16* __restrict__ BT2, float* __restrict__ bqkv) {
    int id = blockIdx.x;
    if (id >= 12288) {
        int i = (id - 12288) * 256 + threadIdx.x;  // 3072
        bqkv[i] = i < 1024 ? bq[i] : (i < 2048 ? bk[i - 1024] : bv[i - 2048]);
        return;
    }
    const float* W; bf16* dst; int K, N, local;
    if (id < 3072)      { int s = id >> 10; W = s == 0 ? Wq : (s == 1 ? Wk : Wv);
                          dst = BTqkv + (size_t)s * 1048576; K = 1024; N = 1024; local = id & 1023; }
    else if (id < 4096) { W = Wo; dst = BTo; K = 1024; N = 1024; local = id - 3072; }
    else if (id < 8192) { W = W1; dst = BT1; K = 1024; N = 4096; local = id - 4096; }
    else                { W = W2; dst = BT2; K = 4096; N = 1024; local = id - 8192; }
    int ls = (N == 4096) ? 7 : 5;                  // log2(N/32)
    int nt = (local & ((1 << ls) - 1)) << 5, kt = (local >> ls) << 5;
    __shared__ float t[32][33];
    int tid = threadIdx.x, r = tid >> 5, c = tid & 31;
#pragma unroll
    for (int p = 0; p < 4; ++p)
        t[r + p * 8][c] = W[(size_t)(kt + r + p * 8) * N + nt + c];
    __syncthreads();
#pragma unroll
    for (int p = 0; p < 4; ++p)
        dst[(size_t)(nt + r + p * 8) * K + kt + c] = tob(t[c][r + p * 8]);
}

// ---------------- MFMA GEMM: C[M,N] = A[M,K] * BT[N,K]^T + bias -------------
#define EPI_RES  1  // fp32 out = acc + bias + resid(fp32)   (out may alias resid)
#define EPI_GELU 2  // bf16 out = gelu(acc + bias)
#define EPI_QKV  3  // q/k: +bias, rope -> QK (stride 2048); v: -> VT transposed
#define EPI_PART 4  // fp32 out = acc (split-K partial, out += z*M*N)

template <int EPI, int MT>
__global__ __launch_bounds__(256, MT == 128 ? 2 : 3) void gemm_bt(
    const bf16* __restrict__ A, const bf16* __restrict__ BT,
    const float* __restrict__ bias, const float* resid, void* out, void* out2,
    int M, int N, int K, int kLen) {
    constexpr int NJ = (MT == 128) ? 4 : 2;
    __shared__ bf16 As[MT * 32];
    __shared__ bf16 Bs[128 * 32];
    const int tid = threadIdx.x;
    const int w = tid >> 6, lane = tid & 63;
    const int quad = lane >> 4, l16 = lane & 15;
    const int rowBase = blockIdx.y * MT, colBase = blockIdx.x * 128;
    const int kStart = blockIdx.z * kLen;
    const int wr = (MT == 128) ? (w >> 1) * 64 : 0;
    const int wc = (MT == 128) ? (w & 1) * 64 : w * 32;
    const int sr = lane >> 2, skb = (lane & 3) * 8;
    f32x4 acc[4][NJ] = {};
    for (int k0 = 0; k0 < kLen; k0 += 32) {
        __syncthreads();
        if (MT == 128) {
#pragma unroll
            for (int t = 0; t < 2; ++t) {
                int inst = w * 2 + t;
                int r = inst * 16 + sr;
                stage16(A  + (size_t)(rowBase + r) * K + kStart + k0 + skb, As + inst * 512);
                stage16(BT + (size_t)(colBase + r) * K + kStart + k0 + skb, Bs + inst * 512);
            }
        } else {
            stage16(A + (size_t)(rowBase + w * 16 + sr) * K + kStart + k0 + skb, As + w * 512);
#pragma unroll
            for (int t = 0; t < 2; ++t) {
                int inst = w + t * 4;
                stage16(BT + (size_t)(colBase + inst * 16 + sr) * K + kStart + k0 + skb, Bs + inst * 512);
            }
        }
        __syncthreads();
        const bf16* pa = As + (wr + l16) * 32 + quad * 8;
        const bf16* pb = Bs + (wc + l16) * 32 + quad * 8;
        short8 a[4], b[NJ];
#pragma unroll
        for (int i = 0; i < 4; ++i) a[i] = *(const short8*)(pa + i * 512);
#pragma unroll
        for (int j = 0; j < NJ; ++j) b[j] = *(const short8*)(pb + j * 512);
#pragma unroll
        for (int i = 0; i < 4; ++i)
#pragma unroll
            for (int j = 0; j < NJ; ++j) acc[i][j] = mfma16(a[i], b[j], acc[i][j]);
    }
    if (EPI == EPI_QKV) {
        bf16* QKo = (bf16*)out;   // (S, 2048) roped q|k
        bf16* VTo = (bf16*)out2;  // (H*64, S)
        if (colBase >= 2048) {  // V section: write transposed VT[c-2048][s]
#pragma unroll
            for (int j = 0; j < NJ; ++j) {
                int c = colBase + wc + j * 16 + l16;
                float bj = bias[c];
                size_t cc = (size_t)(c - 2048) * 4096;
#pragma unroll
                for (int i = 0; i < 4; ++i) {
                    int r0 = rowBase + wr + i * 16 + quad * 4;
                    s16x4 ov = {tobs(acc[i][j][0] + bj), tobs(acc[i][j][1] + bj),
                                tobs(acc[i][j][2] + bj), tobs(acc[i][j][3] + bj)};
                    *(s16x4*)(VTo + cc + r0) = ov;
                }
            }
        } else {  // Q or K section: bias + rope (pairs are (j, j+2) in-lane)
            const bool isq = colBase < 1024;
            const float qs = isq ? 0.125f * 1.44269504088896f : 1.f;
#pragma unroll
            for (int j2 = 0; j2 < 2; ++j2) {
                int dim = j2 * 16 + l16;
                float freq = __expf(-(float)dim * (9.210340371976184f / 32.f));
                int c1 = colBase + wc + j2 * 16 + l16, c2 = c1 + 32;
                float b1v = bias[c1], b2v = bias[c2];
#pragma unroll
                for (int i = 0; i < 4; ++i) {
#pragma unroll
                    for (int reg = 0; reg < 4; ++reg) {
                        int s = rowBase + wr + i * 16 + quad * 4 + reg;
                        float sn, cs;
                        sincosf((float)s * freq, &sn, &cs);
                        float x1 = acc[i][j2][reg] + b1v;
                        float x2 = acc[i][j2 + 2][reg] + b2v;
                        QKo[(size_t)s * 2048 + c1] = tob((x1 * cs - x2 * sn) * qs);
                        QKo[(size_t)s * 2048 + c2] = tob((x2 * cs + x1 * sn) * qs);
                    }
                }
            }
        }
    } else {
#pragma unroll
        for (int j = 0; j < NJ; ++j) {
            int c = colBase + wc + j * 16 + l16;
            float bj = (EPI == EPI_PART) ? 0.f : bias[c];
#pragma unroll
            for (int i = 0; i < 4; ++i) {
                int r0 = rowBase + wr + i * 16 + quad * 4;
#pragma unroll
                for (int reg = 0; reg < 4; ++reg) {
                    size_t idx = (size_t)(r0 + reg) * N + c;
                    float val = acc[i][j][reg] + bj;
                    if (EPI == EPI_RES) {
                        ((float*)out)[idx] = val + resid[idx];
                    } else if (EPI == EPI_PART) {
                        ((float*)out)[(size_t)blockIdx.z * M * N + idx] = val;
                    } else {
                        float g = 0.5f * val * (1.f + erff(val * 0.70710678118f));
                        ((bf16*)out)[idx] = tob(g);
                    }
                }
            }
        }
    }
}

// ---------------- Flash attention v7: 32 q/wave, kt-split-2, fp32 partials --
// grid = H * (S/128) * 2; block = 4 waves, each 32 q-rows over one kt-half.
// Single-buffered 64-key K/V LDS tiles (32 KB -> 4 blocks/CU at grid 1024).
__global__ __launch_bounds__(256, 4) void attn_kernel(const bf16* __restrict__ QK,
                                                      const bf16* __restrict__ VT,
                                                      float* __restrict__ Op,
                                                      float* __restrict__ lp) {
    const int bx = blockIdx.x;
    const int h = bx >> 6, qb = (bx & 63) >> 1, kh = bx & 1;
    const int w = threadIdx.x >> 6, lane = threadIdx.x & 63;
    const int quad = lane >> 4, l16 = lane & 15;
    const int q0w = qb * 128 + w * 32;
    const bf16* Qh = QK + h * 64;
    const bf16* Kh = QK + 1024 + h * 64;
    const bf16* Vh = VT + (size_t)h * 64 * 4096;

    // LDS 32 KiB: Ks 8K (64 keys x 64 hd) | Vs 8K (64 hd x 64 keys) | P 4x4K
    __shared__ char smem[32768];
    bf16* Ks = (bf16*)(smem);
    bf16* Vs = (bf16*)(smem + 8192);
    char* Pw = smem + 16384 + w * 4096;  // per-wave P^T: 32 q x 64 keys

    const int sw = l16 & 7;                       // frag XOR swizzle key (row&7)
    const int rloc = lane >> 3, slot = lane & 7;  // staging: 8 rows x 8 chunks
    const int schunk = (slot ^ rloc) * 8;
    const int row0 = w * 16 + rloc, row1 = w * 16 + 8 + rloc;

    // Q frags (loop-invariant): B-operand n=l16 (q), k=quad*8+j (hd)
    short8 qf[2][2];
#pragma unroll
    for (int qt = 0; qt < 2; ++qt)
#pragma unroll
        for (int c = 0; c < 2; ++c)
            qf[qt][c] = *(const short8*)(Qh + (size_t)(q0w + qt * 16 + l16) * 2048 + c * 32 + quad * 8);

    // ones A-fragment: row m=0 all-ones -> accl row 0 = sum_k P[k][q] = l
    const short ob = (l16 == 0) ? (short)0x3F80 : (short)0;
    const short8 ones8 = {ob, ob, ob, ob, ob, ob, ob, ob};

    f32x4 acc[4][2] = {};
    f32x4 accl[2] = {};
    const f32x4 zero = {0.f, 0.f, 0.f, 0.f};
    const int ktBeg = kh * 2048;

    for (int kt = 0; kt < 2048; kt += 64) {
        const int ktA = ktBeg + kt;
        __syncthreads();  // previous iter's tile reads complete
        stage16(Kh + (size_t)(ktA + row0) * 2048 + schunk, Ks + w * 1024);
        stage16(Kh + (size_t)(ktA + row1) * 2048 + schunk, Ks + w * 1024 + 512);
        stage16(Vh + (size_t)row0 * 4096 + ktA + schunk, Vs + w * 1024);
        stage16(Vh + (size_t)row1 * 4096 + ktA + schunk, Vs + w * 1024 + 512);
        __syncthreads();  // DMA drained (vmcnt(0) before barrier)

        // S^T: A = K rows (m=key), B = Q (n=q); 16 mfmas
        f32x4 st[4][2];
#pragma unroll
        for (int nt = 0; nt < 4; ++nt) {
            const bf16* kr = Ks + (nt * 16 + l16) * 64;
            short8 k0 = *(const short8*)(kr + ((quad ^ sw) * 8));
            short8 k1 = *(const short8*)(kr + (((quad + 4) ^ sw) * 8));
#pragma unroll
            for (int qt = 0; qt < 2; ++qt)
                st[nt][qt] = mfma16(k1, qf[qt][1], mfma16(k0, qf[qt][0], zero));
        }
        // P^T = exp2(S^T): lane holds keys nt*16+quad*4+{0..3} of q=qt*16+l16
#pragma unroll
        for (int nt = 0; nt < 4; ++nt)
#pragma unroll
            for (int qt = 0; qt < 2; ++qt) {
                float e0 = EXP2(st[nt][qt][0]), e1 = EXP2(st[nt][qt][1]);
                float e2 = EXP2(st[nt][qt][2]), e3 = EXP2(st[nt][qt][3]);
                uint2 pk = {pkbf16(e0, e1), pkbf16(e2, e3)};
                *(uint2*)(Pw + (qt * 16 + l16) * 128 +
                          (((nt * 2 + (quad >> 1)) ^ sw) * 16) + (quad & 1) * 8) = pk;
            }
        asm volatile("s_waitcnt lgkmcnt(0)" ::: "memory");
        // PV: A = V^T (m=vdim), B = P^T (n=q, k=key); 16 + 4 ones mfmas
#pragma unroll
        for (int c = 0; c < 2; ++c) {
            short8 pB[2];
#pragma unroll
            for (int qt = 0; qt < 2; ++qt) {
                pB[qt] = *(const short8*)(Pw + (qt * 16 + l16) * 128 + (((c * 4 + quad) ^ sw) * 16));
                accl[qt] = mfma16(ones8, pB[qt], accl[qt]);
            }
#pragma unroll
            for (int vt = 0; vt < 4; ++vt) {
                short8 vf = *(const short8*)(Vs + (vt * 16 + l16) * 64 + (((c * 4 + quad) ^ sw) * 8));
#pragma unroll
                for (int qt = 0; qt < 2; ++qt)
                    acc[vt][qt] = mfma16(vf, pB[qt], acc[vt][qt]);
            }
        }
    }
    // write fp32 partials; l[q] is accl[qt] reg0 at quad 0, lane q=l16
    float* Oz = Op + (size_t)kh * (4096 * 1024);
#pragma unroll
    for (int qt = 0; qt < 2; ++qt) {
        int q = q0w + qt * 16 + l16;
#pragma unroll
        for (int vt = 0; vt < 4; ++vt)
            *(f32x4*)(Oz + (size_t)q * 1024 + h * 64 + vt * 16 + quad * 4) = acc[vt][qt];
        if (quad == 0) lp[kh * 65536 + h * 4096 + q] = accl[qt][0];
    }
}

// ---------------- attn partial merge: o = (Op0+Op1)/(l0+l1), bf16 out -------
__global__ __launch_bounds__(256) void merge_attn(const float* __restrict__ Op,
                                                  const float* __restrict__ lp,
                                                  bf16* __restrict__ o) {
    int i = blockIdx.x * 256 + threadIdx.x;  // f32x4 index, 4096*1024/4
    int d4 = i * 4;
    int s = d4 >> 10, d = d4 & 1023, h = d >> 6;
    f32x4 a = *(const f32x4*)(Op + d4 + (size_t)s * 0);  // Op[s*1024+d] == Op[d4]
    f32x4 b = *(const f32x4*)(Op + 4194304 + d4);
    float linv = 1.f / (lp[h * 4096 + s] + lp[65536 + h * 4096 + s]);
    s16x4 ov = {tobs(a[0] + b[0]) , 0, 0, 0};
    ov[0] = tobs((a[0] + b[0]) * linv);
    ov[1] = tobs((a[1] + b[1]) * linv);
    ov[2] = tobs((a[2] + b[2]) * linv);
    ov[3] = tobs((a[3] + b[3]) * linv);
    *(s16x4*)(o + d4) = ov;
}

// ---------------- FFN2 split-K merge: out += pb0 + pb1 + b2 (in-place) ------
__global__ __launch_bounds__(256) void merge_ffn2(const float* __restrict__ pb,
                                                  const float* __restrict__ b2,
                                                  float* __restrict__ out) {
    int i = blockIdx.x * 256 + threadIdx.x;  // f32x4 index
    int d4 = i * 4, c = d4 & 1023;
    f32x4 a = *(const f32x4*)(pb + d4);
    f32x4 b = *(const f32x4*)(pb + 4194304 + d4);
    f32x4 r = *(const f32x4*)(out + d4);
    f32x4 bb = *(const f32x4*)(b2 + c);
    f32x4 v = {a[0] + b[0] + r[0] + bb[0], a[1] + b[1] + r[1] + bb[1],
               a[2] + b[2] + r[2] + bb[2], a[3] + b[3] + r[3] + bb[3]};
    *(f32x4*)(out + d4) = v;
}

extern "C" void kernel_launch(void* const* d_in, const int* in_sizes, int n_in,
                              void* d_out, int out_size, void* d_ws, size_t ws_size,
                              hipStream_t stream) {
    const float* x   = (const float*)d_in[0];
    const float* s1  = (const float*)d_in[1];
    const float* b1n = (const float*)d_in[2];
    const float* s2  = (const float*)d_in[3];
    const float* b2n = (const float*)d_in[4];
    const float* Wq  = (const float*)d_in[5];
    const float* bq  = (const float*)d_in[6];
    const float* Wk  = (const float*)d_in[7];
    const float* bk  = (const float*)d_in[8];
    const float* Wv  = (const float*)d_in[9];
    const float* bv  = (const float*)d_in[10];
    const float* Wo  = (const float*)d_in[11];
    const float* bo  = (const float*)d_in[12];
    const float* W1  = (const float*)d_in[13];
    const float* b1  = (const float*)d_in[14];
    const float* W2  = (const float*)d_in[15];
    const float* b2  = (const float*)d_in[16];

    char* ws = (char*)d_ws;                       // 96 MiB budget
    bf16*  y    = (bf16*)(ws);                    // 0-8: ln outs
    bf16*  QK   = (bf16*)(ws + (8ull  << 20));    // 8-24: roped q|k, stride 2048
    bf16*  BTo  = (bf16*)(ws + (24ull << 20));    // 24-26
    float* lp   = (float*)(ws + (26ull << 20));   // 26-26.5: attn l partials [2][H][S]
    float* bqkv = (float*)(ws + (27ull << 20));   // 27: 12KB
    bf16*  o    = (bf16*)(ws + (32ull << 20));    // 32-40: merged attn out
    bf16*  hb   = (bf16*)(ws + (40ull << 20));    // 40-72: FFN hidden
    bf16*  BTqkv= (bf16*)(ws + (40ull << 20));    // 40-46 (dead after QKV gemm)
    float* Op   = (float*)(ws + (40ull << 20));   // 40-72: attn O partials [2][S][D]
    bf16*  VT   = (bf16*)(ws + (72ull << 20));    // 72-80
    bf16*  BT1  = (bf16*)(ws + (80ull << 20));    // 80-88
    bf16*  BT2  = (bf16*)(ws + (88ull << 20));    // 88-96
    float* pb   = (float*)(ws);                   // 0-32: FFN2 split-K partials
    float* x1   = (float*)d_out;                  // fp32 residual lives in d_out

    wtrans_all<<<12300, 256, 0, stream>>>(Wq, Wk, Wv, Wo, W1, W2, bq, bk, bv,
                                          BTqkv, BTo, BT1, BT2, bqkv);

    ln_kernel<<<S, 256, 0, stream>>>(x, s1, b1n, y);

    // fused QKV GEMM with rope epilogue; q,k -> QK (stride 2048), V -> VT
    gemm_bt<EPI_QKV, 128><<<dim3(24, 32), 256, 0, stream>>>(y, BTqkv, bqkv, nullptr, QK, VT, S, 3072, D, D);

    attn_kernel<<<H * 64, 256, 0, stream>>>(QK, VT, Op, lp);
    merge_attn<<<4096, 256, 0, stream>>>(Op, lp, o);

    // O projection + residual (fp32) -> x1 (= d_out)
    gemm_bt<EPI_RES, 64><<<dim3(8, 64), 256, 0, stream>>>(o, BTo, bo, x, x1, nullptr, S, D, D, D);

    ln_kernel<<<S, 256, 0, stream>>>(x1, s2, b2n, y);

    // FFN1 + GELU
    gemm_bt<EPI_GELU, 128><<<dim3(32, 32), 256, 0, stream>>>(y, BT1, b1, nullptr, hb, nullptr, S, FF, D, D);

    // FFN2 split-K=2 -> fp32 partials, then merge with bias + residual
    gemm_bt<EPI_PART, 64><<<dim3(8, 64, 2), 256, 0, stream>>>(hb, BT2, b2, nullptr, pb, nullptr, S, D, FF, 2048);
    merge_ffn2<<<4096, 256, 0, stream>>>(pb, b2, x1);
}